// Round 14
// baseline (183.848 us; speedup 1.0000x reference)
//
#include <hip/hip_runtime.h>
#include <hip/hip_bf16.h>
#include <cstdint>
#include <cstddef>

#define NQ_ 32768
#define DM_ 256
#define DFF_ 1024
#define LNB_ 16
#define NB_ 8

typedef __attribute__((ext_vector_type(4))) float f32x4;
typedef __attribute__((ext_vector_type(8))) short s16x8;

__device__ __forceinline__ float bf2f(ushort u) {
    union { unsigned int i; float f; } c; c.i = ((unsigned int)u) << 16; return c.f;
}
__device__ __forceinline__ ushort f2bf(float f) {
    union { float f; unsigned int i; } c; c.f = f;
    unsigned int x = c.i;
    return (ushort)((x + 0x7fffu + ((x >> 16) & 1u)) >> 16); // RNE
}

// ---------------- prep kernels ----------------

__global__ __launch_bounds__(256) void prep_qk(const float* __restrict__ src, const float* __restrict__ pos,
                                               ushort* __restrict__ qkb, ushort* __restrict__ srcb) {
    int i = (blockIdx.x * 256 + threadIdx.x) * 4;
    float4 s = *(const float4*)(src + i);
    float4 p = *(const float4*)(pos + i);
    ushort4 a, b;
    a.x = f2bf(s.x + p.x); a.y = f2bf(s.y + p.y); a.z = f2bf(s.z + p.z); a.w = f2bf(s.w + p.w);
    b.x = f2bf(s.x);       b.y = f2bf(s.y);       b.z = f2bf(s.z);       b.w = f2bf(s.w);
    *(ushort4*)(qkb + i) = a;
    *(ushort4*)(srcb + i) = b;
}

// weight transposes (f32 [K][N] -> bf16 [N][K]) + batch-offset scan + fused QK bias
__global__ __launch_bounds__(256) void prep_weights(const float* __restrict__ Wq, const float* __restrict__ Wk,
                                                    const float* __restrict__ Wv, const float* __restrict__ Wo,
                                                    const float* __restrict__ W1, const float* __restrict__ W2,
                                                    const int* __restrict__ kbc,
                                                    const float* __restrict__ bq, const float* __restrict__ bk,
                                                    ushort* __restrict__ WqT, ushort* __restrict__ WkT,
                                                    ushort* __restrict__ WvT, ushort* __restrict__ WoT,
                                                    ushort* __restrict__ W1T, ushort* __restrict__ W2T,
                                                    int* __restrict__ offs, float* __restrict__ bias2) {
    const int b = blockIdx.x;
    const int t = threadIdx.x;
    if (b == 3072) {
        if (t == 0) { int a = 0; for (int i = 0; i < NB_; ++i) { offs[i] = a; a += kbc[i]; } }
        bias2[t] = bq[t];
        bias2[256 + t] = bk[t];
        return;
    }
    const float* W; ushort* Wt; int base, ks, ns;
    if (b < 1024) {           // 4x [256][256]
        const int sec = b >> 8;
        W  = sec == 0 ? Wq  : sec == 1 ? Wk  : sec == 2 ? Wv  : Wo;
        Wt = sec == 0 ? WqT : sec == 1 ? WkT : sec == 2 ? WvT : WoT;
        base = (b & 255) * 256; ks = 8; ns = 8;
    } else if (b < 2048) {    // W1 [256][1024]
        W = W1; Wt = W1T; base = (b - 1024) * 256; ks = 8; ns = 10;
    } else {                  // W2 [1024][256]
        W = W2; Wt = W2T; base = (b - 2048) * 256; ks = 10; ns = 8;
    }
    const int i = base + t;
    const int n = i >> ks, k = i & ((1 << ks) - 1);
    Wt[i] = f2bf(W[(k << ns) + n]);
}

// ---------------- GEMM (round-7 structure): 2-phase dbuf, counted vmcnt, chunk swizzle, XCD strip ----------------

__device__ __forceinline__ void gld_lds16(const ushort* g, ushort* l) {
    __builtin_amdgcn_global_load_lds((const __attribute__((address_space(1))) void*)g,
                                     (__attribute__((address_space(3))) void*)l, 16, 0, 0);
}

template <bool RELU>
__global__ __launch_bounds__(256) void gemm_kernel(const ushort* __restrict__ A, const ushort* __restrict__ Bt,
                                                   const float* __restrict__ bias, ushort* __restrict__ C,
                                                   int M, int N, int K, float alpha) {
    __shared__ __align__(16) ushort As[2 * 128 * 32];
    __shared__ __align__(16) ushort Bs[2 * 128 * 32];
    const int tid = threadIdx.x;
    const int lane = tid & 63;
    const int wave = tid >> 6;
    const int wr = wave >> 1, wc = wave & 1;

    // XCD-locality swizzle (requires gridDim.x == 256): b -> xcd strip of 32 m-tiles
    const int b = (int)(blockIdx.y * gridDim.x + blockIdx.x);
    const int idx = b >> 3;
    const int xt = (b & 7) * 32 + (idx & 31);
    const int yt = idx >> 5;
    const long m0 = (long)xt * 128;
    const long n0 = (long)yt * 128;

    f32x4 acc[4][4] = {};

    const int c0 = tid, c1 = tid + 256;
    const int ar0 = c0 >> 2, ac0 = c0 & 3;
    const int ar1 = c1 >> 2, ac1 = c1 & 3;
    const int as0 = (ac0 ^ ((ar0 >> 1) & 3)) * 8;   // pre-swizzled global chunk offset
    const int as1 = (ac1 ^ ((ar1 >> 1) & 3)) * 8;
    const int la = lane & 15;
    const int sx = ((lane >> 4) ^ ((la >> 1) & 3)) * 8;  // swizzled read chunk offset

    const ushort* Ar0 = A + (m0 + ar0) * K + as0;
    const ushort* Ar1 = A + (m0 + ar1) * K + as1;
    const ushort* Br0 = Bt + (n0 + ar0) * K + as0;
    const ushort* Br1 = Bt + (n0 + ar1) * K + as1;

    const int nt = K >> 5;
    int boff = 0;
    gld_lds16(Ar0, As + c0 * 8);
    gld_lds16(Ar1, As + c1 * 8);
    gld_lds16(Br0, Bs + c0 * 8);
    gld_lds16(Br1, Bs + c1 * 8);

    for (int t = 0; t < nt; ++t) {
        if (t + 1 < nt) {
            const int kt = (t + 1) << 5;
            const int nb = boff ^ 4096;
            gld_lds16(Ar0 + kt, As + nb + c0 * 8);
            gld_lds16(Ar1 + kt, As + nb + c1 * 8);
            gld_lds16(Br0 + kt, Bs + nb + c0 * 8);
            gld_lds16(Br1 + kt, Bs + nb + c1 * 8);
            asm volatile("s_waitcnt vmcnt(4)" ::: "memory");   // current tile landed; next stays in flight
        } else {
            asm volatile("s_waitcnt vmcnt(0)" ::: "memory");
        }
        __builtin_amdgcn_s_barrier();
        s16x8 af[4], bfr[4];
#pragma unroll
        for (int m = 0; m < 4; ++m)
            af[m] = *(const s16x8*)(As + boff + (wr * 64 + m * 16 + la) * 32 + sx);
#pragma unroll
        for (int n = 0; n < 4; ++n)
            bfr[n] = *(const s16x8*)(Bs + boff + (wc * 64 + n * 16 + la) * 32 + sx);
        asm volatile("s_waitcnt lgkmcnt(0)" ::: "memory");     // my reads done before anyone overwrites
        __builtin_amdgcn_s_barrier();
#pragma unroll
        for (int m = 0; m < 4; ++m)
#pragma unroll
            for (int n = 0; n < 4; ++n)
                acc[m][n] = __builtin_amdgcn_mfma_f32_16x16x32_bf16(af[m], bfr[n], acc[m][n], 0, 0, 0);
        boff ^= 4096;
    }

#pragma unroll
    for (int n = 0; n < 4; ++n) {
        const long col = n0 + wc * 64 + n * 16 + la;
        const float bv = bias[col];
#pragma unroll
        for (int m = 0; m < 4; ++m) {
#pragma unroll
            for (int j = 0; j < 4; ++j) {
                const long row = m0 + wr * 64 + m * 16 + (lane >> 4) * 4 + j;
                float r = (acc[m][n][j] + bv) * alpha;
                if (RELU) r = fmaxf(r, 0.f);
                C[row * N + col] = f2bf(r);
            }
        }
    }
}

// ---------------- fused GEMM + residual + LayerNorm: 128 rows x 256 cols, 8 waves ----------------
// 512 threads, wave (wr=wave>>2, wc=wave&3) owns a 64x64 tile; BK=32 double-buffered with
// counted vmcnt(3) (1 A + 2 B chunks/thread in flight). LDS 48 KB -> 2 blocks/CU (16 waves/CU).
// Halves per-output B-panel staging vs the 64-row version (B staged once per 128 rows).
// Staging: A chunk = tid (row=tid>>2, rel=tid&3); B chunks = tid, tid+512 (rows tid>>2, tid>>2+128).
// Source rel-swizzle ((tid&3)^((tid>>3)&3)) is row-map invariant (both +128 and panel offsets
// contribute 0 mod 4 to (row>>1)). LN row stats: intra-wave 16-lane shfl -> red[4][128] by wc
// (aliased into dead As) -> sum over wc.

template <bool F32OUT>
__global__ __launch_bounds__(512, 4) void gemm_ln_kernel(const ushort* __restrict__ A, const ushort* __restrict__ Bt,
                                                         const float* __restrict__ bias,
                                                         const ushort* __restrict__ resid,
                                                         const float* __restrict__ g, const float* __restrict__ be,
                                                         void* __restrict__ outv, int K) {
    __shared__ __align__(16) ushort As[2 * 128 * 32];   // 16 KB
    __shared__ __align__(16) ushort Bs[2 * 256 * 32];   // 32 KB
    const int tid = threadIdx.x;
    const int lane = tid & 63;
    const int wave = tid >> 6;          // 0..7
    const int wr = wave >> 2;           // 0..1  (m half)
    const int wc = wave & 3;            // 0..3  (n quarter)
    const long m0 = (long)blockIdx.x * 128;

    const int rel8 = ((tid & 3) ^ ((tid >> 3) & 3)) * 8;   // row-map-invariant source k-swizzle
    const int arow = tid >> 2;                              // 0..127
    const ushort* Asrc  = A + (m0 + arow) * K + rel8;
    const ushort* Bsrc0 = Bt + (long)arow * K + rel8;
    const ushort* Bsrc1 = Bt + (long)(arow + 128) * K + rel8;

    const int la = lane & 15;
    const int sx = ((lane >> 4) ^ ((la >> 1) & 3)) * 8;

    f32x4 acc[4][4] = {};
    const int nt = K >> 5;
    int buf = 0;
    // prologue: stage tile 0
    gld_lds16(Asrc, As + tid * 8);
    gld_lds16(Bsrc0, Bs + tid * 8);
    gld_lds16(Bsrc1, Bs + (tid + 512) * 8);

    for (int t = 0; t < nt; ++t) {
        const int bA = buf * 4096, bB = buf * 8192;
        if (t + 1 < nt) {
            const int kt = (t + 1) << 5;
            const int nA = (buf ^ 1) * 4096, nB = (buf ^ 1) * 8192;
            gld_lds16(Asrc + kt, As + nA + tid * 8);
            gld_lds16(Bsrc0 + kt, Bs + nB + tid * 8);
            gld_lds16(Bsrc1 + kt, Bs + nB + (tid + 512) * 8);
            asm volatile("s_waitcnt vmcnt(3)" ::: "memory");   // tile t landed; t+1's 3 loads in flight
        } else {
            asm volatile("s_waitcnt vmcnt(0)" ::: "memory");
        }
        __builtin_amdgcn_s_barrier();
        s16x8 af[4], bfr[4];
#pragma unroll
        for (int m = 0; m < 4; ++m)
            af[m] = *(const s16x8*)(As + bA + (wr * 64 + m * 16 + la) * 32 + sx);
#pragma unroll
        for (int n = 0; n < 4; ++n)
            bfr[n] = *(const s16x8*)(Bs + bB + (wc * 64 + n * 16 + la) * 32 + sx);
        asm volatile("s_waitcnt lgkmcnt(0)" ::: "memory");
        __builtin_amdgcn_s_barrier();
#pragma unroll
        for (int m = 0; m < 4; ++m)
#pragma unroll
            for (int n = 0; n < 4; ++n)
                acc[m][n] = __builtin_amdgcn_mfma_f32_16x16x32_bf16(af[m], bfr[n], acc[m][n], 0, 0, 0);
        buf ^= 1;
    }

    // epilogue: LN reduce arrays alias dead As (all waves' LDS reads done before last barrier)
    float* red_s = (float*)As;          // [4 wc][128 rows]
    float* red_q = (float*)As + 512;
    const int rg4 = (lane >> 4) * 4;
    float bv[4];
#pragma unroll
    for (int n = 0; n < 4; ++n) bv[n] = bias[wc * 64 + n * 16 + la];

#pragma unroll
    for (int m = 0; m < 4; ++m) {
#pragma unroll
        for (int j = 0; j < 4; ++j) {
            const int grow = wr * 64 + m * 16 + rg4 + j;   // block-local row 0..127
            float s = 0.f, q = 0.f;
#pragma unroll
            for (int n = 0; n < 4; ++n) {
                const int col = wc * 64 + n * 16 + la;
                float v = acc[m][n][j] + bv[n] + bf2f(resid[(m0 + grow) * DM_ + col]);
                acc[m][n][j] = v;
                s += v; q += v * v;
            }
#pragma unroll
            for (int mk = 1; mk < 16; mk <<= 1) { s += __shfl_xor(s, mk); q += __shfl_xor(q, mk); }
            if (la == 0) { red_s[wc * 128 + grow] = s; red_q[wc * 128 + grow] = q; }
        }
    }
    __syncthreads();

    float gv[4], bev[4];
#pragma unroll
    for (int n = 0; n < 4; ++n) {
        const int col = wc * 64 + n * 16 + la;
        gv[n] = g[col]; bev[n] = be[col];
    }
#pragma unroll
    for (int m = 0; m < 4; ++m) {
#pragma unroll
        for (int j = 0; j < 4; ++j) {
            const int grow = wr * 64 + m * 16 + rg4 + j;
            const float s = red_s[grow] + red_s[128 + grow] + red_s[256 + grow] + red_s[384 + grow];
            const float q = red_q[grow] + red_q[128 + grow] + red_q[256 + grow] + red_q[384 + grow];
            const float mu = s * (1.f / 256.f);
            const float rsig = rsqrtf(q * (1.f / 256.f) - mu * mu + 1e-5f);
#pragma unroll
            for (int n = 0; n < 4; ++n) {
                const int col = wc * 64 + n * 16 + la;
                const float r = (acc[m][n][j] - mu) * rsig * gv[n] + bev[n];
                if (F32OUT) ((float*)outv)[(m0 + grow) * DM_ + col] = r;
                else        ((ushort*)outv)[(m0 + grow) * DM_ + col] = f2bf(r);
            }
        }
    }
}

// ---------------- local attention: 32 lanes per query, lane owns 8 contiguous dims ----------------

__global__ __launch_bounds__(256, 4) void attn_kernel(const ushort* __restrict__ QKb,
                                                      const ushort* __restrict__ Vb, const int* __restrict__ ipair,
                                                      const int* __restrict__ ipb, const int* __restrict__ offs,
                                                      ushort* __restrict__ Ob) {
    // grid = 4096 blocks (8 queries each); XCD swizzle: 512 consecutive blocks (one batch) per XCD
    const int blk = (blockIdx.x & 7) * (NQ_ / 8 / 8) + (blockIdx.x >> 3);
    const int lane = threadIdx.x & 63;
    const int n = blk * 8 + (threadIdx.x >> 6) * 2 + (lane >> 5);
    const size_t hoff = (size_t)(lane & 31) * 8;   // 8 ushorts = 16B per lane

    float q[8];
    {
        s16x8 v = *(const s16x8*)(QKb + (size_t)n * 512 + hoff);
#pragma unroll
        for (int e = 0; e < 8; ++e) q[e] = bf2f((ushort)v[e]);
    }
    const int off = offs[ipb[n]];
    int gi[LNB_];
    float lg[LNB_];
#pragma unroll
    for (int j = 0; j < LNB_; ++j) {
        const int ip = ipair[n * LNB_ + j];
        const int g = ip >= 0 ? ip + off : 0;   // reference: invalid -> gather row 0
        gi[j] = g;
        s16x8 v = *(const s16x8*)(QKb + (size_t)g * 512 + 256 + hoff);
        float p = 0.f;
#pragma unroll
        for (int e = 0; e < 8; ++e)
            p = fmaf(q[e], bf2f((ushort)v[e]), p);
        p += __shfl_xor(p, 1);                  // 4-lane head group reduce
        p += __shfl_xor(p, 2);
        lg[j] = ip >= 0 ? p * 0.17677669529663688f : -1e9f;
    }
    float mx = lg[0];
#pragma unroll
    for (int j = 1; j < LNB_; ++j) mx = fmaxf(mx, lg[j]);
    float sum = 0.f, pw[LNB_];
#pragma unroll
    for (int j = 0; j < LNB_; ++j) { pw[j] = __expf(lg[j] - mx); sum += pw[j]; }
    const float inv = 1.f / sum;

    float acc[8] = {};
#pragma unroll
    for (int j = 0; j < LNB_; ++j) {
        s16x8 v = *(const s16x8*)(Vb + (size_t)gi[j] * DM_ + hoff);
        const float w = pw[j] * inv;
#pragma unroll
        for (int e = 0; e < 8; ++e)
            acc[e] = fmaf(w, bf2f((ushort)v[e]), acc[e]);
    }
    s16x8 o;
#pragma unroll
    for (int e = 0; e < 8; ++e) o[e] = (short)f2bf(acc[e]);
    *(s16x8*)(Ob + (size_t)n * DM_ + hoff) = o;
}

// ---------------- launch ----------------

extern "C" void kernel_launch(void* const* d_in, const int* in_sizes, int n_in,
                              void* d_out, int out_size, void* d_ws, size_t ws_size,
                              hipStream_t stream) {
    const float* src = (const float*)d_in[0];
    const float* pos = (const float*)d_in[1];
    const int* ipair = (const int*)d_in[2];
    const int* kbc   = (const int*)d_in[4];
    const int* ipb   = (const int*)d_in[5];
    const float* Wq = (const float*)d_in[6];  const float* bq = (const float*)d_in[7];
    const float* Wk = (const float*)d_in[8];  const float* bk = (const float*)d_in[9];
    const float* Wv = (const float*)d_in[10]; const float* bv = (const float*)d_in[11];
    const float* Wo = (const float*)d_in[12]; const float* bo = (const float*)d_in[13];
    const float* W1 = (const float*)d_in[14]; const float* b1 = (const float*)d_in[15];
    const float* W2 = (const float*)d_in[16]; const float* b2 = (const float*)d_in[17];
    const float* g1 = (const float*)d_in[18]; const float* be1 = (const float*)d_in[19];
    const float* g2 = (const float*)d_in[20]; const float* be2 = (const float*)d_in[21];

    char* ws = (char*)d_ws;
    const size_t SB = (size_t)NQ_ * DM_ * 2;   // 16 MiB per [NQ,256] bf16 buffer
    ushort* qkb  = (ushort*)(ws);              // src+pos bf16; later: attn-out
    ushort* srcb = (ushort*)(ws + SB);         // src bf16; live until Wo+ln1 (residual)
    ushort* QKb  = (ushort*)(ws + 2 * SB);     // fused QK out [NQ,512] (2 SB)
    ushort* Vb   = (ushort*)(ws + 4 * SB);     // V out; later: xb
    ushort* hb   = (ushort*)(ws);              // FF hidden [NQ,1024] spans first 4 SB (all dead by then)
    ushort* attno = qkb;
    ushort* xb    = Vb;                        // Vb dead after attn; Wo+ln1 writes xb here
    char* wb = ws + 6 * SB;
    ushort* WqT = (ushort*)(wb);               // [256][256] — WkT directly after => fused [512][256]
    ushort* WkT = (ushort*)(wb + 131072);
    ushort* WvT = (ushort*)(wb + 262144);
    ushort* WoT = (ushort*)(wb + 393216);
    ushort* W1T = (ushort*)(wb + 524288);
    ushort* W2T = (ushort*)(wb + 1048576);
    int* offs   = (int*)(wb + 1572864);
    float* bias2 = (float*)(wb + 1572864 + 64);

    prep_weights<<<3073, 256, 0, stream>>>(Wq, Wk, Wv, Wo, W1, W2, kbc, bq, bk,
                                           WqT, WkT, WvT, WoT, W1T, W2T, offs, bias2);
    prep_qk<<<NQ_ * DM_ / 4 / 256, 256, 0, stream>>>(src, pos, qkb, srcb);

    dim3 gqk(NQ_ / 128, 512 / 128);
    dim3 g256(NQ_ / 128, DM_ / 128);
    dim3 gff1(NQ_ / 128, DFF_ / 128);
    gemm_kernel<false><<<gqk, 256, 0, stream>>>(qkb, WqT, bias2, QKb, NQ_, 512, DM_, 1.f);
    gemm_kernel<false><<<g256, 256, 0, stream>>>(srcb, WvT, bv, Vb, NQ_, DM_, DM_, 1.f);
    attn_kernel<<<NQ_ / 8, 256, 0, stream>>>(QKb, Vb, ipair, ipb, offs, attno);
    // Wo projection + residual(srcb) + LN1 -> xb (bf16)
    gemm_ln_kernel<false><<<NQ_ / 128, 512, 0, stream>>>(attno, WoT, bo, srcb, g1, be1, (void*)xb, DM_);
    gemm_kernel<true><<<gff1, 256, 0, stream>>>(xb, W1T, b1, hb, NQ_, DFF_, DM_, 1.f);
    // FF2 + residual(xb) + LN2 -> d_out (f32)
    gemm_ln_kernel<true><<<NQ_ / 128, 512, 0, stream>>>(hb, W2T, b2, xb, g2, be2, d_out, DFF_);
}

// Round 15
// 172.197 us; speedup vs baseline: 1.0677x; 1.0677x over previous
//
#include <hip/hip_runtime.h>
#include <hip/hip_bf16.h>
#include <cstdint>
#include <cstddef>

#define NQ_ 32768
#define DM_ 256
#define DFF_ 1024
#define LNB_ 16
#define NB_ 8

typedef __attribute__((ext_vector_type(4))) float f32x4;
typedef __attribute__((ext_vector_type(8))) short s16x8;

__device__ __forceinline__ float bf2f(ushort u) {
    union { unsigned int i; float f; } c; c.i = ((unsigned int)u) << 16; return c.f;
}
__device__ __forceinline__ ushort f2bf(float f) {
    union { float f; unsigned int i; } c; c.f = f;
    unsigned int x = c.i;
    return (ushort)((x + 0x7fffu + ((x >> 16) & 1u)) >> 16); // RNE
}

// ---------------- merged prep: src/pos cast+add (blocks 0..8191) + weight transposes (8192..11264) ----------------

__global__ __launch_bounds__(256) void prep_all(const float* __restrict__ src, const float* __restrict__ pos,
                                                ushort* __restrict__ qkb, ushort* __restrict__ srcb,
                                                const float* __restrict__ Wq, const float* __restrict__ Wk,
                                                const float* __restrict__ Wv, const float* __restrict__ Wo,
                                                const float* __restrict__ W1, const float* __restrict__ W2,
                                                const int* __restrict__ kbc,
                                                const float* __restrict__ bq, const float* __restrict__ bk,
                                                ushort* __restrict__ WqT, ushort* __restrict__ WkT,
                                                ushort* __restrict__ WvT, ushort* __restrict__ WoT,
                                                ushort* __restrict__ W1T, ushort* __restrict__ W2T,
                                                int* __restrict__ offs, float* __restrict__ bias2) {
    const int blk = blockIdx.x;
    const int t = threadIdx.x;
    if (blk < 8192) {
        const int i = (blk * 256 + t) * 4;
        float4 s = *(const float4*)(src + i);
        float4 p = *(const float4*)(pos + i);
        ushort4 a, b;
        a.x = f2bf(s.x + p.x); a.y = f2bf(s.y + p.y); a.z = f2bf(s.z + p.z); a.w = f2bf(s.w + p.w);
        b.x = f2bf(s.x);       b.y = f2bf(s.y);       b.z = f2bf(s.z);       b.w = f2bf(s.w);
        *(ushort4*)(qkb + i) = a;
        *(ushort4*)(srcb + i) = b;
        return;
    }
    const int b = blk - 8192;
    if (b == 3072) {
        if (t == 0) { int a = 0; for (int i = 0; i < NB_; ++i) { offs[i] = a; a += kbc[i]; } }
        bias2[t] = bq[t];
        bias2[256 + t] = bk[t];
        return;
    }
    const float* W; ushort* Wt; int base, ks, ns;
    if (b < 1024) {           // 4x [256][256]
        const int sec = b >> 8;
        W  = sec == 0 ? Wq  : sec == 1 ? Wk  : sec == 2 ? Wv  : Wo;
        Wt = sec == 0 ? WqT : sec == 1 ? WkT : sec == 2 ? WvT : WoT;
        base = (b & 255) * 256; ks = 8; ns = 8;
    } else if (b < 2048) {    // W1 [256][1024]
        W = W1; Wt = W1T; base = (b - 1024) * 256; ks = 8; ns = 10;
    } else {                  // W2 [1024][256]
        W = W2; Wt = W2T; base = (b - 2048) * 256; ks = 10; ns = 8;
    }
    const int i = base + t;
    const int n = i >> ks, k = i & ((1 << ks) - 1);
    Wt[i] = f2bf(W[(k << ns) + n]);
}

// ---------------- GEMM (round-7 structure): 2-phase dbuf, counted vmcnt, chunk swizzle, XCD strip ----------------

__device__ __forceinline__ void gld_lds16(const ushort* g, ushort* l) {
    __builtin_amdgcn_global_load_lds((const __attribute__((address_space(1))) void*)g,
                                     (__attribute__((address_space(3))) void*)l, 16, 0, 0);
}

template <bool RELU>
__global__ __launch_bounds__(256) void gemm_kernel(const ushort* __restrict__ A, const ushort* __restrict__ Bt,
                                                   const float* __restrict__ bias, ushort* __restrict__ C,
                                                   int M, int N, int K, float alpha) {
    __shared__ __align__(16) ushort As[2 * 128 * 32];
    __shared__ __align__(16) ushort Bs[2 * 128 * 32];
    const int tid = threadIdx.x;
    const int lane = tid & 63;
    const int wave = tid >> 6;
    const int wr = wave >> 1, wc = wave & 1;

    // XCD-locality swizzle (requires gridDim.x == 256): b -> xcd strip of 32 m-tiles
    const int b = (int)(blockIdx.y * gridDim.x + blockIdx.x);
    const int idx = b >> 3;
    const int xt = (b & 7) * 32 + (idx & 31);
    const int yt = idx >> 5;
    const long m0 = (long)xt * 128;
    const long n0 = (long)yt * 128;

    f32x4 acc[4][4] = {};

    const int c0 = tid, c1 = tid + 256;
    const int ar0 = c0 >> 2, ac0 = c0 & 3;
    const int ar1 = c1 >> 2, ac1 = c1 & 3;
    const int as0 = (ac0 ^ ((ar0 >> 1) & 3)) * 8;   // pre-swizzled global chunk offset
    const int as1 = (ac1 ^ ((ar1 >> 1) & 3)) * 8;
    const int la = lane & 15;
    const int sx = ((lane >> 4) ^ ((la >> 1) & 3)) * 8;  // swizzled read chunk offset

    const ushort* Ar0 = A + (m0 + ar0) * K + as0;
    const ushort* Ar1 = A + (m0 + ar1) * K + as1;
    const ushort* Br0 = Bt + (n0 + ar0) * K + as0;
    const ushort* Br1 = Bt + (n0 + ar1) * K + as1;

    const int nt = K >> 5;
    int boff = 0;
    gld_lds16(Ar0, As + c0 * 8);
    gld_lds16(Ar1, As + c1 * 8);
    gld_lds16(Br0, Bs + c0 * 8);
    gld_lds16(Br1, Bs + c1 * 8);

    for (int t = 0; t < nt; ++t) {
        if (t + 1 < nt) {
            const int kt = (t + 1) << 5;
            const int nb = boff ^ 4096;
            gld_lds16(Ar0 + kt, As + nb + c0 * 8);
            gld_lds16(Ar1 + kt, As + nb + c1 * 8);
            gld_lds16(Br0 + kt, Bs + nb + c0 * 8);
            gld_lds16(Br1 + kt, Bs + nb + c1 * 8);
            asm volatile("s_waitcnt vmcnt(4)" ::: "memory");   // current tile landed; next stays in flight
        } else {
            asm volatile("s_waitcnt vmcnt(0)" ::: "memory");
        }
        __builtin_amdgcn_s_barrier();
        s16x8 af[4], bfr[4];
#pragma unroll
        for (int m = 0; m < 4; ++m)
            af[m] = *(const s16x8*)(As + boff + (wr * 64 + m * 16 + la) * 32 + sx);
#pragma unroll
        for (int n = 0; n < 4; ++n)
            bfr[n] = *(const s16x8*)(Bs + boff + (wc * 64 + n * 16 + la) * 32 + sx);
        asm volatile("s_waitcnt lgkmcnt(0)" ::: "memory");     // my reads done before anyone overwrites
        __builtin_amdgcn_s_barrier();
#pragma unroll
        for (int m = 0; m < 4; ++m)
#pragma unroll
            for (int n = 0; n < 4; ++n)
                acc[m][n] = __builtin_amdgcn_mfma_f32_16x16x32_bf16(af[m], bfr[n], acc[m][n], 0, 0, 0);
        boff ^= 4096;
    }

#pragma unroll
    for (int n = 0; n < 4; ++n) {
        const long col = n0 + wc * 64 + n * 16 + la;
        const float bv = bias[col];
#pragma unroll
        for (int m = 0; m < 4; ++m) {
#pragma unroll
            for (int j = 0; j < 4; ++j) {
                const long row = m0 + wr * 64 + m * 16 + (lane >> 4) * 4 + j;
                float r = (acc[m][n][j] + bv) * alpha;
                if (RELU) r = fmaxf(r, 0.f);
                C[row * N + col] = f2bf(r);
            }
        }
    }
}

// ---------------- merged QK + V projection GEMM: grid (256, 6) ----------------
// yt<4: QK path (A=qkb, Bt=fused [512][256] Wq|Wk, C=QKb[N=512]); yt>=4: V path.
// Body identical to gemm_kernel (K=256 fixed, alpha=1, no act). Block-uniform branch.
// Per-y-slice XCD swizzle: each XCD owns 32 contiguous m-tiles within each y-slice.

__global__ __launch_bounds__(256) void qkv_kernel(const ushort* __restrict__ qkb, const ushort* __restrict__ srcb,
                                                  const ushort* __restrict__ WqkT, const ushort* __restrict__ WvT,
                                                  const float* __restrict__ bias2, const float* __restrict__ bv,
                                                  ushort* __restrict__ QKb, ushort* __restrict__ Vb) {
    __shared__ __align__(16) ushort As[2 * 128 * 32];
    __shared__ __align__(16) ushort Bs[2 * 128 * 32];
    const int tid = threadIdx.x;
    const int lane = tid & 63;
    const int wave = tid >> 6;
    const int wr = wave >> 1, wc = wave & 1;
    const int K = DM_;

    const bool isqk = blockIdx.y < 4;
    const ushort* A  = isqk ? qkb : srcb;
    const ushort* Bt = isqk ? WqkT : WvT;
    const float* bias = isqk ? bias2 : bv;
    ushort* C = isqk ? QKb : Vb;
    const int N = isqk ? 512 : 256;
    const int bx = (int)blockIdx.x;
    const int xt = (bx & 7) * 32 + (bx >> 3);          // XCD m-strip swizzle within the slice
    const long m0 = (long)xt * 128;
    const long n0 = (long)(isqk ? blockIdx.y : (blockIdx.y - 4)) * 128;

    f32x4 acc[4][4] = {};

    const int c0 = tid, c1 = tid + 256;
    const int ar0 = c0 >> 2, ac0 = c0 & 3;
    const int ar1 = c1 >> 2, ac1 = c1 & 3;
    const int as0 = (ac0 ^ ((ar0 >> 1) & 3)) * 8;
    const int as1 = (ac1 ^ ((ar1 >> 1) & 3)) * 8;
    const int la = lane & 15;
    const int sx = ((lane >> 4) ^ ((la >> 1) & 3)) * 8;

    const ushort* Ar0 = A + (m0 + ar0) * K + as0;
    const ushort* Ar1 = A + (m0 + ar1) * K + as1;
    const ushort* Br0 = Bt + (n0 + ar0) * K + as0;
    const ushort* Br1 = Bt + (n0 + ar1) * K + as1;

    const int nt = K >> 5;   // 8
    int boff = 0;
    gld_lds16(Ar0, As + c0 * 8);
    gld_lds16(Ar1, As + c1 * 8);
    gld_lds16(Br0, Bs + c0 * 8);
    gld_lds16(Br1, Bs + c1 * 8);

    for (int t = 0; t < nt; ++t) {
        if (t + 1 < nt) {
            const int kt = (t + 1) << 5;
            const int nb = boff ^ 4096;
            gld_lds16(Ar0 + kt, As + nb + c0 * 8);
            gld_lds16(Ar1 + kt, As + nb + c1 * 8);
            gld_lds16(Br0 + kt, Bs + nb + c0 * 8);
            gld_lds16(Br1 + kt, Bs + nb + c1 * 8);
            asm volatile("s_waitcnt vmcnt(4)" ::: "memory");
        } else {
            asm volatile("s_waitcnt vmcnt(0)" ::: "memory");
        }
        __builtin_amdgcn_s_barrier();
        s16x8 af[4], bfr[4];
#pragma unroll
        for (int m = 0; m < 4; ++m)
            af[m] = *(const s16x8*)(As + boff + (wr * 64 + m * 16 + la) * 32 + sx);
#pragma unroll
        for (int n = 0; n < 4; ++n)
            bfr[n] = *(const s16x8*)(Bs + boff + (wc * 64 + n * 16 + la) * 32 + sx);
        asm volatile("s_waitcnt lgkmcnt(0)" ::: "memory");
        __builtin_amdgcn_s_barrier();
#pragma unroll
        for (int m = 0; m < 4; ++m)
#pragma unroll
            for (int n = 0; n < 4; ++n)
                acc[m][n] = __builtin_amdgcn_mfma_f32_16x16x32_bf16(af[m], bfr[n], acc[m][n], 0, 0, 0);
        boff ^= 4096;
    }

#pragma unroll
    for (int n = 0; n < 4; ++n) {
        const long col = n0 + wc * 64 + n * 16 + la;
        const float bvv = bias[col];
#pragma unroll
        for (int m = 0; m < 4; ++m) {
#pragma unroll
            for (int j = 0; j < 4; ++j) {
                const long row = m0 + wr * 64 + m * 16 + (lane >> 4) * 4 + j;
                C[row * N + col] = f2bf(acc[m][n][j] + bvv);
            }
        }
    }
}

// ---------------- fused GEMM + residual + LayerNorm, 2-phase pipelined, BK=64 (round-13) ----------------

template <bool F32OUT>
__global__ __launch_bounds__(256) void gemm_ln_kernel(const ushort* __restrict__ A, const ushort* __restrict__ Bt,
                                                      const float* __restrict__ bias,
                                                      const ushort* __restrict__ resid,
                                                      const float* __restrict__ g, const float* __restrict__ be,
                                                      void* __restrict__ outv, int K) {
    __shared__ __align__(16) ushort As[2 * 2 * 64 * 32];    // 16 KB: [buf][panel][64 rows][32 k]
    __shared__ __align__(16) ushort Bs[2 * 2 * 256 * 32];   // 64 KB: [buf][panel][256 rows][32 k]
    const int tid = threadIdx.x;
    const int lane = tid & 63;
    const int wave = tid >> 6;
    const long m0 = (long)blockIdx.x * 64;

    const int rel8 = ((tid & 3) ^ ((tid >> 3) & 3)) * 8;   // panel-invariant source k-swizzle
    const int arow = tid >> 2;                              // A row this thread stages
    const ushort* Asrc = A + (m0 + arow) * K + rel8;        // + panel*32 + kt at use
    const ushort* Bsrc[4];                                  // B rows: tid>>2 + 64*j
#pragma unroll
    for (int j = 0; j < 4; ++j)
        Bsrc[j] = Bt + (long)(arow + 64 * j) * K + rel8;

    const int la = lane & 15;
    const int sx = ((lane >> 4) ^ ((la >> 1) & 3)) * 8;

    f32x4 acc[4][4] = {};
    const int nt = K >> 6;
    int buf = 0;
    // prologue: stage tile 0 (A: panels 0,1; B: panels 0,1 x 4 row-groups)
#pragma unroll
    for (int p = 0; p < 2; ++p)
        gld_lds16(Asrc + p * 32, As + (p * 256 + tid) * 8);
#pragma unroll
    for (int i = 0; i < 8; ++i)
        gld_lds16(Bsrc[i & 3] + (i >> 2) * 32, Bs + ((i >> 2) * 1024 + (i & 3) * 256 + tid) * 8);

    for (int t = 0; t < nt; ++t) {
        const int bA = buf * 4096, bB = buf * 16384;
        if (t + 1 < nt) {
            const int kt = (t + 1) << 6;
            const int nA = (buf ^ 1) * 4096, nB = (buf ^ 1) * 16384;
#pragma unroll
            for (int p = 0; p < 2; ++p)
                gld_lds16(Asrc + kt + p * 32, As + nA + (p * 256 + tid) * 8);
#pragma unroll
            for (int i = 0; i < 8; ++i)
                gld_lds16(Bsrc[i & 3] + kt + (i >> 2) * 32, Bs + nB + ((i >> 2) * 1024 + (i & 3) * 256 + tid) * 8);
            asm volatile("s_waitcnt vmcnt(10)" ::: "memory");  // tile t landed; t+1's 10 loads in flight
        } else {
            asm volatile("s_waitcnt vmcnt(0)" ::: "memory");
        }
        __builtin_amdgcn_s_barrier();
        s16x8 af[2][4], bfr[2][4];
#pragma unroll
        for (int kk = 0; kk < 2; ++kk) {
#pragma unroll
            for (int m = 0; m < 4; ++m)
                af[kk][m] = *(const s16x8*)(As + bA + kk * 2048 + (m * 16 + la) * 32 + sx);
#pragma unroll
            for (int n = 0; n < 4; ++n)
                bfr[kk][n] = *(const s16x8*)(Bs + bB + kk * 8192 + (wave * 64 + n * 16 + la) * 32 + sx);
        }
        asm volatile("s_waitcnt lgkmcnt(0)" ::: "memory");
        __builtin_amdgcn_s_barrier();
#pragma unroll
        for (int kk = 0; kk < 2; ++kk)
#pragma unroll
            for (int m = 0; m < 4; ++m)
#pragma unroll
                for (int n = 0; n < 4; ++n)
                    acc[m][n] = __builtin_amdgcn_mfma_f32_16x16x32_bf16(af[kk][m], bfr[kk][n], acc[m][n], 0, 0, 0);
        buf ^= 1;
    }

    // epilogue: LN reduce arrays alias dead As (all LDS reads completed before the last barrier)
    float* red_s = (float*)As;          // [4][64]
    float* red_q = (float*)As + 256;    // [4][64]
    const int rg4 = (lane >> 4) * 4;
    float bv[4];
#pragma unroll
    for (int n = 0; n < 4; ++n) bv[n] = bias[wave * 64 + n * 16 + la];

#pragma unroll
    for (int m = 0; m < 4; ++m) {
#pragma unroll
        for (int j = 0; j < 4; ++j) {
            const int lr = m * 16 + rg4 + j;
            float s = 0.f, q = 0.f;
#pragma unroll
            for (int n = 0; n < 4; ++n) {
                const int col = wave * 64 + n * 16 + la;
                float v = acc[m][n][j] + bv[n] + bf2f(resid[(m0 + lr) * DM_ + col]);
                acc[m][n][j] = v;
                s += v; q += v * v;
            }
#pragma unroll
            for (int mk = 1; mk < 16; mk <<= 1) { s += __shfl_xor(s, mk); q += __shfl_xor(q, mk); }
            if (la == 0) { red_s[wave * 64 + lr] = s; red_q[wave * 64 + lr] = q; }
        }
    }
    __syncthreads();

    float gv[4], bev[4];
#pragma unroll
    for (int n = 0; n < 4; ++n) {
        const int col = wave * 64 + n * 16 + la;
        gv[n] = g[col]; bev[n] = be[col];
    }
#pragma unroll
    for (int m = 0; m < 4; ++m) {
#pragma unroll
        for (int j = 0; j < 4; ++j) {
            const int lr = m * 16 + rg4 + j;
            const float s = red_s[lr] + red_s[64 + lr] + red_s[128 + lr] + red_s[192 + lr];
            const float q = red_q[lr] + red_q[64 + lr] + red_q[128 + lr] + red_q[192 + lr];
            const float mu = s * (1.f / 256.f);
            const float rsig = rsqrtf(q * (1.f / 256.f) - mu * mu + 1e-5f);
#pragma unroll
            for (int n = 0; n < 4; ++n) {
                const int col = wave * 64 + n * 16 + la;
                const float r = (acc[m][n][j] - mu) * rsig * gv[n] + bev[n];
                if (F32OUT) ((float*)outv)[(m0 + lr) * DM_ + col] = r;
                else        ((ushort*)outv)[(m0 + lr) * DM_ + col] = f2bf(r);
            }
        }
    }
}

// ---------------- local attention: 32 lanes per query, lane owns 8 contiguous dims ----------------

__global__ __launch_bounds__(256, 4) void attn_kernel(const ushort* __restrict__ QKb,
                                                      const ushort* __restrict__ Vb, const int* __restrict__ ipair,
                                                      const int* __restrict__ ipb, const int* __restrict__ offs,
                                                      ushort* __restrict__ Ob) {
    // grid = 4096 blocks (8 queries each); XCD swizzle: 512 consecutive blocks (one batch) per XCD
    const int blk = (blockIdx.x & 7) * (NQ_ / 8 / 8) + (blockIdx.x >> 3);
    const int lane = threadIdx.x & 63;
    const int n = blk * 8 + (threadIdx.x >> 6) * 2 + (lane >> 5);
    const size_t hoff = (size_t)(lane & 31) * 8;   // 8 ushorts = 16B per lane

    float q[8];
    {
        s16x8 v = *(const s16x8*)(QKb + (size_t)n * 512 + hoff);
#pragma unroll
        for (int e = 0; e < 8; ++e) q[e] = bf2f((ushort)v[e]);
    }
    const int off = offs[ipb[n]];
    int gi[LNB_];
    float lg[LNB_];
#pragma unroll
    for (int j = 0; j < LNB_; ++j) {
        const int ip = ipair[n * LNB_ + j];
        const int g = ip >= 0 ? ip + off : 0;   // reference: invalid -> gather row 0
        gi[j] = g;
        s16x8 v = *(const s16x8*)(QKb + (size_t)g * 512 + 256 + hoff);
        float p = 0.f;
#pragma unroll
        for (int e = 0; e < 8; ++e)
            p = fmaf(q[e], bf2f((ushort)v[e]), p);
        p += __shfl_xor(p, 1);                  // 4-lane head group reduce
        p += __shfl_xor(p, 2);
        lg[j] = ip >= 0 ? p * 0.17677669529663688f : -1e9f;
    }
    float mx = lg[0];
#pragma unroll
    for (int j = 1; j < LNB_; ++j) mx = fmaxf(mx, lg[j]);
    float sum = 0.f, pw[LNB_];
#pragma unroll
    for (int j = 0; j < LNB_; ++j) { pw[j] = __expf(lg[j] - mx); sum += pw[j]; }
    const float inv = 1.f / sum;

    float acc[8] = {};
#pragma unroll
    for (int j = 0; j < LNB_; ++j) {
        s16x8 v = *(const s16x8*)(Vb + (size_t)gi[j] * DM_ + hoff);
        const float w = pw[j] * inv;
#pragma unroll
        for (int e = 0; e < 8; ++e)
            acc[e] = fmaf(w, bf2f((ushort)v[e]), acc[e]);
    }
    s16x8 o;
#pragma unroll
    for (int e = 0; e < 8; ++e) o[e] = (short)f2bf(acc[e]);
    *(s16x8*)(Ob + (size_t)n * DM_ + hoff) = o;
}

// ---------------- launch ----------------

extern "C" void kernel_launch(void* const* d_in, const int* in_sizes, int n_in,
                              void* d_out, int out_size, void* d_ws, size_t ws_size,
                              hipStream_t stream) {
    const float* src = (const float*)d_in[0];
    const float* pos = (const float*)d_in[1];
    const int* ipair = (const int*)d_in[2];
    const int* kbc   = (const int*)d_in[4];
    const int* ipb   = (const int*)d_in[5];
    const float* Wq = (const float*)d_in[6];  const float* bq = (const float*)d_in[7];
    const float* Wk = (const float*)d_in[8];  const float* bk = (const float*)d_in[9];
    const float* Wv = (const float*)d_in[10]; const float* bv = (const float*)d_in[11];
    const float* Wo = (const float*)d_in[12]; const float* bo = (const float*)d_in[13];
    const float* W1 = (const float*)d_in[14]; const float* b1 = (const float*)d_in[15];
    const float* W2 = (const float*)d_in[16]; const float* b2 = (const float*)d_in[17];
    const float* g1 = (const float*)d_in[18]; const float* be1 = (const float*)d_in[19];
    const float* g2 = (const float*)d_in[20]; const float* be2 = (const float*)d_in[21];

    char* ws = (char*)d_ws;
    const size_t SB = (size_t)NQ_ * DM_ * 2;   // 16 MiB per [NQ,256] bf16 buffer
    ushort* qkb  = (ushort*)(ws);              // src+pos bf16; later: attn-out
    ushort* srcb = (ushort*)(ws + SB);         // src bf16; live until Wo+ln1 (residual)
    ushort* QKb  = (ushort*)(ws + 2 * SB);     // fused QK out [NQ,512] (2 SB)
    ushort* Vb   = (ushort*)(ws + 4 * SB);     // V out; later: xb
    ushort* hb   = (ushort*)(ws);              // FF hidden [NQ,1024] spans first 4 SB (all dead by then)
    ushort* attno = qkb;
    ushort* xb    = Vb;                        // Vb dead after attn; Wo+ln1 writes xb here
    char* wb = ws + 6 * SB;
    ushort* WqT = (ushort*)(wb);               // [256][256] — WkT directly after => fused [512][256]
    ushort* WkT = (ushort*)(wb + 131072);
    ushort* WvT = (ushort*)(wb + 262144);
    ushort* WoT = (ushort*)(wb + 393216);
    ushort* W1T = (ushort*)(wb + 524288);
    ushort* W2T = (ushort*)(wb + 1048576);
    int* offs   = (int*)(wb + 1572864);
    float* bias2 = (float*)(wb + 1572864 + 64);

    prep_all<<<8192 + 3073, 256, 0, stream>>>(src, pos, qkb, srcb,
                                              Wq, Wk, Wv, Wo, W1, W2, kbc, bq, bk,
                                              WqT, WkT, WvT, WoT, W1T, W2T, offs, bias2);

    dim3 gqkv(256, 6);
    dim3 gff1(NQ_ / 128, DFF_ / 128);
    qkv_kernel<<<gqkv, 256, 0, stream>>>(qkb, srcb, WqT, WvT, bias2, bv, QKb, Vb);
    attn_kernel<<<NQ_ / 8, 256, 0, stream>>>(QKb, Vb, ipair, ipb, offs, attno);
    // Wo projection + residual(srcb) + LN1 -> xb (bf16)
    gemm_ln_kernel<false><<<NQ_ / 64, 256, 0, stream>>>(attno, WoT, bo, srcb, g1, be1, (void*)xb, DM_);
    gemm_kernel<true><<<gff1, 256, 0, stream>>>(xb, W1T, b1, hb, NQ_, DFF_, DM_, 1.f);
    // FF2 + residual(xb) + LN2 -> d_out (f32)
    gemm_ln_kernel<true><<<NQ_ / 64, 256, 0, stream>>>(hb, W2T, b2, xb, g2, be2, d_out, DFF_);
}

// Round 16
// 165.115 us; speedup vs baseline: 1.1135x; 1.0429x over previous
//
#include <hip/hip_runtime.h>
#include <hip/hip_bf16.h>
#include <cstdint>
#include <cstddef>

#define NQ_ 32768
#define DM_ 256
#define DFF_ 1024
#define LNB_ 16
#define NB_ 8

typedef __attribute__((ext_vector_type(4))) float f32x4;
typedef __attribute__((ext_vector_type(8))) short s16x8;

__device__ __forceinline__ float bf2f(ushort u) {
    union { unsigned int i; float f; } c; c.i = ((unsigned int)u) << 16; return c.f;
}
__device__ __forceinline__ ushort f2bf(float f) {
    union { float f; unsigned int i; } c; c.f = f;
    unsigned int x = c.i;
    return (ushort)((x + 0x7fffu + ((x >> 16) & 1u)) >> 16); // RNE
}

// ---------------- merged prep: src/pos cast+add (blocks 0..8191) + weight transposes (8192..11264) ----------------

__global__ __launch_bounds__(256) void prep_all(const float* __restrict__ src, const float* __restrict__ pos,
                                                ushort* __restrict__ qkb, ushort* __restrict__ srcb,
                                                const float* __restrict__ Wq, const float* __restrict__ Wk,
                                                const float* __restrict__ Wv, const float* __restrict__ Wo,
                                                const float* __restrict__ W1, const float* __restrict__ W2,
                                                const int* __restrict__ kbc,
                                                const float* __restrict__ bq, const float* __restrict__ bk,
                                                ushort* __restrict__ WqT, ushort* __restrict__ WkT,
                                                ushort* __restrict__ WvT, ushort* __restrict__ WoT,
                                                ushort* __restrict__ W1T, ushort* __restrict__ W2T,
                                                int* __restrict__ offs, float* __restrict__ bias2) {
    const int blk = blockIdx.x;
    const int t = threadIdx.x;
    if (blk < 8192) {
        const int i = (blk * 256 + t) * 4;
        float4 s = *(const float4*)(src + i);
        float4 p = *(const float4*)(pos + i);
        ushort4 a, b;
        a.x = f2bf(s.x + p.x); a.y = f2bf(s.y + p.y); a.z = f2bf(s.z + p.z); a.w = f2bf(s.w + p.w);
        b.x = f2bf(s.x);       b.y = f2bf(s.y);       b.z = f2bf(s.z);       b.w = f2bf(s.w);
        *(ushort4*)(qkb + i) = a;
        *(ushort4*)(srcb + i) = b;
        return;
    }
    const int b = blk - 8192;
    if (b == 3072) {
        if (t == 0) { int a = 0; for (int i = 0; i < NB_; ++i) { offs[i] = a; a += kbc[i]; } }
        bias2[t] = bq[t];
        bias2[256 + t] = bk[t];
        return;
    }
    const float* W; ushort* Wt; int base, ks, ns;
    if (b < 1024) {           // 4x [256][256]
        const int sec = b >> 8;
        W  = sec == 0 ? Wq  : sec == 1 ? Wk  : sec == 2 ? Wv  : Wo;
        Wt = sec == 0 ? WqT : sec == 1 ? WkT : sec == 2 ? WvT : WoT;
        base = (b & 255) * 256; ks = 8; ns = 8;
    } else if (b < 2048) {    // W1 [256][1024]
        W = W1; Wt = W1T; base = (b - 1024) * 256; ks = 8; ns = 10;
    } else {                  // W2 [1024][256]
        W = W2; Wt = W2T; base = (b - 2048) * 256; ks = 10; ns = 8;
    }
    const int i = base + t;
    const int n = i >> ks, k = i & ((1 << ks) - 1);
    Wt[i] = f2bf(W[(k << ns) + n]);
}

// ---------------- shared GEMM machinery ----------------

__device__ __forceinline__ void gld_lds16(const ushort* g, ushort* l) {
    __builtin_amdgcn_global_load_lds((const __attribute__((address_space(1))) void*)g,
                                     (__attribute__((address_space(3))) void*)l, 16, 0, 0);
}

// ---------------- GEMM, BK=64 (round-13 panel scheme on the 128x128 tile) ----------------
// 2 k-panels of [128 rows][32 k] per buffer (proven conflict-free row stride 64B);
// panel-invariant source swizzle rel8 = ((tid&3)^((tid>>3)&3))*8 (rows tid>>2 and 64+tid>>2
// give the same (row>>1)&3). 8 chunks/thread/K-step -> vmcnt(8). LDS 64 KB.

template <bool RELU>
__global__ __launch_bounds__(256) void gemm_kernel(const ushort* __restrict__ A, const ushort* __restrict__ Bt,
                                                   const float* __restrict__ bias, ushort* __restrict__ C,
                                                   int M, int N, int K, float alpha) {
    __shared__ __align__(16) ushort As[2 * 2 * 128 * 32];   // 32 KB: [buf][panel][128][32]
    __shared__ __align__(16) ushort Bs[2 * 2 * 128 * 32];   // 32 KB
    const int tid = threadIdx.x;
    const int lane = tid & 63;
    const int wave = tid >> 6;
    const int wr = wave >> 1, wc = wave & 1;

    // XCD-locality swizzle (requires gridDim.x == 256): b -> xcd strip of 32 m-tiles
    const int b = (int)(blockIdx.y * gridDim.x + blockIdx.x);
    const int idx = b >> 3;
    const int xt = (b & 7) * 32 + (idx & 31);
    const int yt = idx >> 5;
    const long m0 = (long)xt * 128;
    const long n0 = (long)yt * 128;

    f32x4 acc[4][4] = {};

    const int rel8 = ((tid & 3) ^ ((tid >> 3) & 3)) * 8;
    const ushort* Ar0 = A + (m0 + (tid >> 2)) * K + rel8;
    const ushort* Ar1 = Ar0 + 64 * K;
    const ushort* Br0 = Bt + (n0 + (tid >> 2)) * K + rel8;
    const ushort* Br1 = Br0 + 64 * K;
    const int la = lane & 15;
    const int sx = ((lane >> 4) ^ ((la >> 1) & 3)) * 8;

    const int nt = K >> 6;
    int buf = 0;
    // prologue: stage tile 0 (2 panels x {A lo, A hi, B lo, B hi})
#pragma unroll
    for (int p = 0; p < 2; ++p) {
        gld_lds16(Ar0 + p * 32, As + p * 4096 + tid * 8);
        gld_lds16(Ar1 + p * 32, As + p * 4096 + (tid + 256) * 8);
        gld_lds16(Br0 + p * 32, Bs + p * 4096 + tid * 8);
        gld_lds16(Br1 + p * 32, Bs + p * 4096 + (tid + 256) * 8);
    }

    for (int t = 0; t < nt; ++t) {
        const int bO = buf * 8192;
        if (t + 1 < nt) {
            const int kt = (t + 1) << 6;
            const int nO = (buf ^ 1) * 8192;
#pragma unroll
            for (int p = 0; p < 2; ++p) {
                gld_lds16(Ar0 + kt + p * 32, As + nO + p * 4096 + tid * 8);
                gld_lds16(Ar1 + kt + p * 32, As + nO + p * 4096 + (tid + 256) * 8);
                gld_lds16(Br0 + kt + p * 32, Bs + nO + p * 4096 + tid * 8);
                gld_lds16(Br1 + kt + p * 32, Bs + nO + p * 4096 + (tid + 256) * 8);
            }
            asm volatile("s_waitcnt vmcnt(8)" ::: "memory");   // tile t landed; t+1's 8 loads in flight
        } else {
            asm volatile("s_waitcnt vmcnt(0)" ::: "memory");
        }
        __builtin_amdgcn_s_barrier();
        s16x8 af[2][4], bfr[2][4];
#pragma unroll
        for (int kk = 0; kk < 2; ++kk) {
#pragma unroll
            for (int m = 0; m < 4; ++m)
                af[kk][m] = *(const s16x8*)(As + bO + kk * 4096 + (wr * 64 + m * 16 + la) * 32 + sx);
#pragma unroll
            for (int n = 0; n < 4; ++n)
                bfr[kk][n] = *(const s16x8*)(Bs + bO + kk * 4096 + (wc * 64 + n * 16 + la) * 32 + sx);
        }
        asm volatile("s_waitcnt lgkmcnt(0)" ::: "memory");
        __builtin_amdgcn_s_barrier();
#pragma unroll
        for (int kk = 0; kk < 2; ++kk)
#pragma unroll
            for (int m = 0; m < 4; ++m)
#pragma unroll
                for (int n = 0; n < 4; ++n)
                    acc[m][n] = __builtin_amdgcn_mfma_f32_16x16x32_bf16(af[kk][m], bfr[kk][n], acc[m][n], 0, 0, 0);
        buf ^= 1;
    }

#pragma unroll
    for (int n = 0; n < 4; ++n) {
        const long col = n0 + wc * 64 + n * 16 + la;
        const float bv = bias[col];
#pragma unroll
        for (int m = 0; m < 4; ++m) {
#pragma unroll
            for (int j = 0; j < 4; ++j) {
                const long row = m0 + wr * 64 + m * 16 + (lane >> 4) * 4 + j;
                float r = (acc[m][n][j] + bv) * alpha;
                if (RELU) r = fmaxf(r, 0.f);
                C[row * N + col] = f2bf(r);
            }
        }
    }
}

// ---------------- merged QK + V projection GEMM, BK=64: grid (256, 6) ----------------

__global__ __launch_bounds__(256) void qkv_kernel(const ushort* __restrict__ qkb, const ushort* __restrict__ srcb,
                                                  const ushort* __restrict__ WqkT, const ushort* __restrict__ WvT,
                                                  const float* __restrict__ bias2, const float* __restrict__ bv,
                                                  ushort* __restrict__ QKb, ushort* __restrict__ Vb) {
    __shared__ __align__(16) ushort As[2 * 2 * 128 * 32];
    __shared__ __align__(16) ushort Bs[2 * 2 * 128 * 32];
    const int tid = threadIdx.x;
    const int lane = tid & 63;
    const int wave = tid >> 6;
    const int wr = wave >> 1, wc = wave & 1;
    const int K = DM_;

    const bool isqk = blockIdx.y < 4;
    const ushort* A  = isqk ? qkb : srcb;
    const ushort* Bt = isqk ? WqkT : WvT;
    const float* bias = isqk ? bias2 : bv;
    ushort* C = isqk ? QKb : Vb;
    const int N = isqk ? 512 : 256;
    const int bx = (int)blockIdx.x;
    const int xt = (bx & 7) * 32 + (bx >> 3);          // XCD m-strip swizzle within the slice
    const long m0 = (long)xt * 128;
    const long n0 = (long)(isqk ? blockIdx.y : (blockIdx.y - 4)) * 128;

    f32x4 acc[4][4] = {};

    const int rel8 = ((tid & 3) ^ ((tid >> 3) & 3)) * 8;
    const ushort* Ar0 = A + (m0 + (tid >> 2)) * K + rel8;
    const ushort* Ar1 = Ar0 + 64 * K;
    const ushort* Br0 = Bt + (n0 + (tid >> 2)) * K + rel8;
    const ushort* Br1 = Br0 + 64 * K;
    const int la = lane & 15;
    const int sx = ((lane >> 4) ^ ((la >> 1) & 3)) * 8;

    const int nt = K >> 6;   // 4
    int buf = 0;
#pragma unroll
    for (int p = 0; p < 2; ++p) {
        gld_lds16(Ar0 + p * 32, As + p * 4096 + tid * 8);
        gld_lds16(Ar1 + p * 32, As + p * 4096 + (tid + 256) * 8);
        gld_lds16(Br0 + p * 32, Bs + p * 4096 + tid * 8);
        gld_lds16(Br1 + p * 32, Bs + p * 4096 + (tid + 256) * 8);
    }

    for (int t = 0; t < nt; ++t) {
        const int bO = buf * 8192;
        if (t + 1 < nt) {
            const int kt = (t + 1) << 6;
            const int nO = (buf ^ 1) * 8192;
#pragma unroll
            for (int p = 0; p < 2; ++p) {
                gld_lds16(Ar0 + kt + p * 32, As + nO + p * 4096 + tid * 8);
                gld_lds16(Ar1 + kt + p * 32, As + nO + p * 4096 + (tid + 256) * 8);
                gld_lds16(Br0 + kt + p * 32, Bs + nO + p * 4096 + tid * 8);
                gld_lds16(Br1 + kt + p * 32, Bs + nO + p * 4096 + (tid + 256) * 8);
            }
            asm volatile("s_waitcnt vmcnt(8)" ::: "memory");
        } else {
            asm volatile("s_waitcnt vmcnt(0)" ::: "memory");
        }
        __builtin_amdgcn_s_barrier();
        s16x8 af[2][4], bfr[2][4];
#pragma unroll
        for (int kk = 0; kk < 2; ++kk) {
#pragma unroll
            for (int m = 0; m < 4; ++m)
                af[kk][m] = *(const s16x8*)(As + bO + kk * 4096 + (wr * 64 + m * 16 + la) * 32 + sx);
#pragma unroll
            for (int n = 0; n < 4; ++n)
                bfr[kk][n] = *(const s16x8*)(Bs + bO + kk * 4096 + (wc * 64 + n * 16 + la) * 32 + sx);
        }
        asm volatile("s_waitcnt lgkmcnt(0)" ::: "memory");
        __builtin_amdgcn_s_barrier();
#pragma unroll
        for (int kk = 0; kk < 2; ++kk)
#pragma unroll
            for (int m = 0; m < 4; ++m)
#pragma unroll
                for (int n = 0; n < 4; ++n)
                    acc[m][n] = __builtin_amdgcn_mfma_f32_16x16x32_bf16(af[kk][m], bfr[kk][n], acc[m][n], 0, 0, 0);
        buf ^= 1;
    }

#pragma unroll
    for (int n = 0; n < 4; ++n) {
        const long col = n0 + wc * 64 + n * 16 + la;
        const float bvv = bias[col];
#pragma unroll
        for (int m = 0; m < 4; ++m) {
#pragma unroll
            for (int j = 0; j < 4; ++j) {
                const long row = m0 + wr * 64 + m * 16 + (lane >> 4) * 4 + j;
                C[row * N + col] = f2bf(acc[m][n][j] + bvv);
            }
        }
    }
}

// ---------------- fused GEMM + residual + LayerNorm, 2-phase pipelined, BK=64 (round-13) ----------------

template <bool F32OUT>
__global__ __launch_bounds__(256) void gemm_ln_kernel(const ushort* __restrict__ A, const ushort* __restrict__ Bt,
                                                      const float* __restrict__ bias,
                                                      const ushort* __restrict__ resid,
                                                      const float* __restrict__ g, const float* __restrict__ be,
                                                      void* __restrict__ outv, int K) {
    __shared__ __align__(16) ushort As[2 * 2 * 64 * 32];    // 16 KB: [buf][panel][64 rows][32 k]
    __shared__ __align__(16) ushort Bs[2 * 2 * 256 * 32];   // 64 KB: [buf][panel][256 rows][32 k]
    const int tid = threadIdx.x;
    const int lane = tid & 63;
    const int wave = tid >> 6;
    const long m0 = (long)blockIdx.x * 64;

    const int rel8 = ((tid & 3) ^ ((tid >> 3) & 3)) * 8;   // panel-invariant source k-swizzle
    const int arow = tid >> 2;                              // A row this thread stages
    const ushort* Asrc = A + (m0 + arow) * K + rel8;        // + panel*32 + kt at use
    const ushort* Bsrc[4];                                  // B rows: tid>>2 + 64*j
#pragma unroll
    for (int j = 0; j < 4; ++j)
        Bsrc[j] = Bt + (long)(arow + 64 * j) * K + rel8;

    const int la = lane & 15;
    const int sx = ((lane >> 4) ^ ((la >> 1) & 3)) * 8;

    f32x4 acc[4][4] = {};
    const int nt = K >> 6;
    int buf = 0;
    // prologue: stage tile 0 (A: panels 0,1; B: panels 0,1 x 4 row-groups)
#pragma unroll
    for (int p = 0; p < 2; ++p)
        gld_lds16(Asrc + p * 32, As + (p * 256 + tid) * 8);
#pragma unroll
    for (int i = 0; i < 8; ++i)
        gld_lds16(Bsrc[i & 3] + (i >> 2) * 32, Bs + ((i >> 2) * 1024 + (i & 3) * 256 + tid) * 8);

    for (int t = 0; t < nt; ++t) {
        const int bA = buf * 4096, bB = buf * 16384;
        if (t + 1 < nt) {
            const int kt = (t + 1) << 6;
            const int nA = (buf ^ 1) * 4096, nB = (buf ^ 1) * 16384;
#pragma unroll
            for (int p = 0; p < 2; ++p)
                gld_lds16(Asrc + kt + p * 32, As + nA + (p * 256 + tid) * 8);
#pragma unroll
            for (int i = 0; i < 8; ++i)
                gld_lds16(Bsrc[i & 3] + kt + (i >> 2) * 32, Bs + nB + ((i >> 2) * 1024 + (i & 3) * 256 + tid) * 8);
            asm volatile("s_waitcnt vmcnt(10)" ::: "memory");  // tile t landed; t+1's 10 loads in flight
        } else {
            asm volatile("s_waitcnt vmcnt(0)" ::: "memory");
        }
        __builtin_amdgcn_s_barrier();
        s16x8 af[2][4], bfr[2][4];
#pragma unroll
        for (int kk = 0; kk < 2; ++kk) {
#pragma unroll
            for (int m = 0; m < 4; ++m)
                af[kk][m] = *(const s16x8*)(As + bA + kk * 2048 + (m * 16 + la) * 32 + sx);
#pragma unroll
            for (int n = 0; n < 4; ++n)
                bfr[kk][n] = *(const s16x8*)(Bs + bB + kk * 8192 + (wave * 64 + n * 16 + la) * 32 + sx);
        }
        asm volatile("s_waitcnt lgkmcnt(0)" ::: "memory");
        __builtin_amdgcn_s_barrier();
#pragma unroll
        for (int kk = 0; kk < 2; ++kk)
#pragma unroll
            for (int m = 0; m < 4; ++m)
#pragma unroll
                for (int n = 0; n < 4; ++n)
                    acc[m][n] = __builtin_amdgcn_mfma_f32_16x16x32_bf16(af[kk][m], bfr[kk][n], acc[m][n], 0, 0, 0);
        buf ^= 1;
    }

    // epilogue: LN reduce arrays alias dead As (all LDS reads completed before the last barrier)
    float* red_s = (float*)As;          // [4][64]
    float* red_q = (float*)As + 256;    // [4][64]
    const int rg4 = (lane >> 4) * 4;
    float bv[4];
#pragma unroll
    for (int n = 0; n < 4; ++n) bv[n] = bias[wave * 64 + n * 16 + la];

#pragma unroll
    for (int m = 0; m < 4; ++m) {
#pragma unroll
        for (int j = 0; j < 4; ++j) {
            const int lr = m * 16 + rg4 + j;
            float s = 0.f, q = 0.f;
#pragma unroll
            for (int n = 0; n < 4; ++n) {
                const int col = wave * 64 + n * 16 + la;
                float v = acc[m][n][j] + bv[n] + bf2f(resid[(m0 + lr) * DM_ + col]);
                acc[m][n][j] = v;
                s += v; q += v * v;
            }
#pragma unroll
            for (int mk = 1; mk < 16; mk <<= 1) { s += __shfl_xor(s, mk); q += __shfl_xor(q, mk); }
            if (la == 0) { red_s[wave * 64 + lr] = s; red_q[wave * 64 + lr] = q; }
        }
    }
    __syncthreads();

    float gv[4], bev[4];
#pragma unroll
    for (int n = 0; n < 4; ++n) {
        const int col = wave * 64 + n * 16 + la;
        gv[n] = g[col]; bev[n] = be[col];
    }
#pragma unroll
    for (int m = 0; m < 4; ++m) {
#pragma unroll
        for (int j = 0; j < 4; ++j) {
            const int lr = m * 16 + rg4 + j;
            const float s = red_s[lr] + red_s[64 + lr] + red_s[128 + lr] + red_s[192 + lr];
            const float q = red_q[lr] + red_q[64 + lr] + red_q[128 + lr] + red_q[192 + lr];
            const float mu = s * (1.f / 256.f);
            const float rsig = rsqrtf(q * (1.f / 256.f) - mu * mu + 1e-5f);
#pragma unroll
            for (int n = 0; n < 4; ++n) {
                const int col = wave * 64 + n * 16 + la;
                const float r = (acc[m][n][j] - mu) * rsig * gv[n] + bev[n];
                if (F32OUT) ((float*)outv)[(m0 + lr) * DM_ + col] = r;
                else        ((ushort*)outv)[(m0 + lr) * DM_ + col] = f2bf(r);
            }
        }
    }
}

// ---------------- local attention: 32 lanes per query + V-prefetch into registers ----------------

__global__ __launch_bounds__(256, 3) void attn_kernel(const ushort* __restrict__ QKb,
                                                      const ushort* __restrict__ Vb, const int* __restrict__ ipair,
                                                      const int* __restrict__ ipb, const int* __restrict__ offs,
                                                      ushort* __restrict__ Ob) {
    // grid = 4096 blocks (8 queries each); XCD swizzle: 512 consecutive blocks (one batch) per XCD
    const int blk = (blockIdx.x & 7) * (NQ_ / 8 / 8) + (blockIdx.x >> 3);
    const int lane = threadIdx.x & 63;
    const int n = blk * 8 + (threadIdx.x >> 6) * 2 + (lane >> 5);
    const size_t hoff = (size_t)(lane & 31) * 8;   // 8 ushorts = 16B per lane

    float q[8];
    {
        s16x8 v = *(const s16x8*)(QKb + (size_t)n * 512 + hoff);
#pragma unroll
        for (int e = 0; e < 8; ++e) q[e] = bf2f((ushort)v[e]);
    }
    const int off = offs[ipb[n]];
    float lg[LNB_];
    s16x8 va[LNB_];
#pragma unroll
    for (int j = 0; j < LNB_; ++j) {
        const int ip = ipair[n * LNB_ + j];
        const int g = ip >= 0 ? ip + off : 0;   // reference: invalid -> gather row 0
        s16x8 v = *(const s16x8*)(QKb + (size_t)g * 512 + 256 + hoff);
        va[j] = *(const s16x8*)(Vb + (size_t)g * DM_ + hoff);   // prefetch V alongside K
        float p = 0.f;
#pragma unroll
        for (int e = 0; e < 8; ++e)
            p = fmaf(q[e], bf2f((ushort)v[e]), p);
        p += __shfl_xor(p, 1);                  // 4-lane head group reduce
        p += __shfl_xor(p, 2);
        lg[j] = ip >= 0 ? p * 0.17677669529663688f : -1e9f;
    }
    float mx = lg[0];
#pragma unroll
    for (int j = 1; j < LNB_; ++j) mx = fmaxf(mx, lg[j]);
    float sum = 0.f, pw[LNB_];
#pragma unroll
    for (int j = 0; j < LNB_; ++j) { pw[j] = __expf(lg[j] - mx); sum += pw[j]; }
    const float inv = 1.f / sum;

    float acc[8] = {};
#pragma unroll
    for (int j = 0; j < LNB_; ++j) {
        const float w = pw[j] * inv;
#pragma unroll
        for (int e = 0; e < 8; ++e)
            acc[e] = fmaf(w, bf2f((ushort)va[j][e]), acc[e]);
    }
    s16x8 o;
#pragma unroll
    for (int e = 0; e < 8; ++e) o[e] = (short)f2bf(acc[e]);
    *(s16x8*)(Ob + (size_t)n * DM_ + hoff) = o;
}

// ---------------- launch ----------------

extern "C" void kernel_launch(void* const* d_in, const int* in_sizes, int n_in,
                              void* d_out, int out_size, void* d_ws, size_t ws_size,
                              hipStream_t stream) {
    const float* src = (const float*)d_in[0];
    const float* pos = (const float*)d_in[1];
    const int* ipair = (const int*)d_in[2];
    const int* kbc   = (const int*)d_in[4];
    const int* ipb   = (const int*)d_in[5];
    const float* Wq = (const float*)d_in[6];  const float* bq = (const float*)d_in[7];
    const float* Wk = (const float*)d_in[8];  const float* bk = (const float*)d_in[9];
    const float* Wv = (const float*)d_in[10]; const float* bv = (const float*)d_in[11];
    const float* Wo = (const float*)d_in[12]; const float* bo = (const float*)d_in[13];
    const float* W1 = (const float*)d_in[14]; const float* b1 = (const float*)d_in[15];
    const float* W2 = (const float*)d_in[16]; const float* b2 = (const float*)d_in[17];
    const float* g1 = (const float*)d_in[18]; const float* be1 = (const float*)d_in[19];
    const float* g2 = (const float*)d_in[20]; const float* be2 = (const float*)d_in[21];

    char* ws = (char*)d_ws;
    const size_t SB = (size_t)NQ_ * DM_ * 2;   // 16 MiB per [NQ,256] bf16 buffer
    ushort* qkb  = (ushort*)(ws);              // src+pos bf16; later: attn-out
    ushort* srcb = (ushort*)(ws + SB);         // src bf16; live until Wo+ln1 (residual)
    ushort* QKb  = (ushort*)(ws + 2 * SB);     // fused QK out [NQ,512] (2 SB)
    ushort* Vb   = (ushort*)(ws + 4 * SB);     // V out; later: xb
    ushort* hb   = (ushort*)(ws);              // FF hidden [NQ,1024] spans first 4 SB (all dead by then)
    ushort* attno = qkb;
    ushort* xb    = Vb;                        // Vb dead after attn; Wo+ln1 writes xb here
    char* wb = ws + 6 * SB;
    ushort* WqT = (ushort*)(wb);               // [256][256] — WkT directly after => fused [512][256]
    ushort* WkT = (ushort*)(wb + 131072);
    ushort* WvT = (ushort*)(wb + 262144);
    ushort* WoT = (ushort*)(wb + 393216);
    ushort* W1T = (ushort*)(wb + 524288);
    ushort* W2T = (ushort*)(wb + 1048576);
    int* offs   = (int*)(wb + 1572864);
    float* bias2 = (float*)(wb + 1572864 + 64);

    prep_all<<<8192 + 3073, 256, 0, stream>>>(src, pos, qkb, srcb,
                                              Wq, Wk, Wv, Wo, W1, W2, kbc, bq, bk,
                                              WqT, WkT, WvT, WoT, W1T, W2T, offs, bias2);

    dim3 gqkv(256, 6);
    dim3 gff1(NQ_ / 128, DFF_ / 128);
    qkv_kernel<<<gqkv, 256, 0, stream>>>(qkb, srcb, WqT, WvT, bias2, bv, QKb, Vb);
    attn_kernel<<<NQ_ / 8, 256, 0, stream>>>(QKb, Vb, ipair, ipb, offs, attno);
    // Wo projection + residual(srcb) + LN1 -> xb (bf16)
    gemm_ln_kernel<false><<<NQ_ / 64, 256, 0, stream>>>(attno, WoT, bo, srcb, g1, be1, (void*)xb, DM_);
    gemm_kernel<true><<<gff1, 256, 0, stream>>>(xb, W1T, b1, hb, NQ_, DFF_, DM_, 1.f);
    // FF2 + residual(xb) + LN2 -> d_out (f32)
    gemm_ln_kernel<true><<<NQ_ / 64, 256, 0, stream>>>(hb, W2T, b2, xb, g2, be2, d_out, DFF_);
}

// Round 17
// 163.595 us; speedup vs baseline: 1.1238x; 1.0093x over previous
//
#include <hip/hip_runtime.h>
#include <hip/hip_bf16.h>
#include <cstdint>
#include <cstddef>

#define NQ_ 32768
#define DM_ 256
#define DFF_ 1024
#define LNB_ 16
#define NB_ 8

typedef __attribute__((ext_vector_type(4))) float f32x4;
typedef __attribute__((ext_vector_type(8))) short s16x8;

__device__ __forceinline__ float bf2f(ushort u) {
    union { unsigned int i; float f; } c; c.i = ((unsigned int)u) << 16; return c.f;
}
__device__ __forceinline__ ushort f2bf(float f) {
    union { float f; unsigned int i; } c; c.f = f;
    unsigned int x = c.i;
    return (ushort)((x + 0x7fffu + ((x >> 16) & 1u)) >> 16); // RNE
}

// ---------------- merged prep ----------------
// blocks 0..8191: src/pos cast+add (coalesced float4)
// blocks 8192..8383: weight transposes via LDS-tiled 64x64 transpose (coalesced both sides;
//   the old per-element version read W at 1KB stride = ~16x line over-fetch)
// block 8384: batch-offset scan + fused QK bias

__global__ __launch_bounds__(256) void prep_all(const float* __restrict__ src, const float* __restrict__ pos,
                                                ushort* __restrict__ qkb, ushort* __restrict__ srcb,
                                                const float* __restrict__ Wq, const float* __restrict__ Wk,
                                                const float* __restrict__ Wv, const float* __restrict__ Wo,
                                                const float* __restrict__ W1, const float* __restrict__ W2,
                                                const int* __restrict__ kbc,
                                                const float* __restrict__ bq, const float* __restrict__ bk,
                                                ushort* __restrict__ WqT, ushort* __restrict__ WkT,
                                                ushort* __restrict__ WvT, ushort* __restrict__ WoT,
                                                ushort* __restrict__ W1T, ushort* __restrict__ W2T,
                                                int* __restrict__ offs, float* __restrict__ bias2) {
    const int blk = blockIdx.x;
    const int t = threadIdx.x;
    if (blk < 8192) {
        const int i = (blk * 256 + t) * 4;
        float4 s = *(const float4*)(src + i);
        float4 p = *(const float4*)(pos + i);
        ushort4 a, b;
        a.x = f2bf(s.x + p.x); a.y = f2bf(s.y + p.y); a.z = f2bf(s.z + p.z); a.w = f2bf(s.w + p.w);
        b.x = f2bf(s.x);       b.y = f2bf(s.y);       b.z = f2bf(s.z);       b.w = f2bf(s.w);
        *(ushort4*)(qkb + i) = a;
        *(ushort4*)(srcb + i) = b;
        return;
    }
    if (blk == 8384) {
        if (t == 0) { int a = 0; for (int i = 0; i < NB_; ++i) { offs[i] = a; a += kbc[i]; } }
        bias2[t] = bq[t];
        bias2[256 + t] = bk[t];
        return;
    }
    // ---- tiled transpose: W [K][N] f32 -> Wt [N][K] bf16, 64x64 tiles ----
    __shared__ float tile[64][65];
    const int tb = blk - 8192;        // 0..191
    const float* W; ushort* Wt; int K, N, kt, ntl;
    if (tb < 64) {                    // Wq/Wk/Wv/Wo [256][256]
        const int sec = tb >> 4;
        W  = sec == 0 ? Wq  : sec == 1 ? Wk  : sec == 2 ? Wv  : Wo;
        Wt = sec == 0 ? WqT : sec == 1 ? WkT : sec == 2 ? WvT : WoT;
        K = 256; N = 256; kt = (tb & 15) >> 2; ntl = tb & 3;
    } else if (tb < 128) {            // W1 [256][1024]
        W = W1; Wt = W1T; K = 256; N = 1024;
        const int r = tb - 64; kt = r >> 4; ntl = r & 15;
    } else {                          // W2 [1024][256]
        W = W2; Wt = W2T; K = 1024; N = 256;
        const int r = tb - 128; kt = r >> 2; ntl = r & 3;
    }
    const int k0 = kt * 64, n0 = ntl * 64;
    const int r16 = t >> 4, c4 = (t & 15) * 4;
#pragma unroll
    for (int p = 0; p < 4; ++p) {
        const int row = p * 16 + r16;
        float4 v = *(const float4*)(W + (long)(k0 + row) * N + n0 + c4);
        tile[row][c4] = v.x; tile[row][c4 + 1] = v.y; tile[row][c4 + 2] = v.z; tile[row][c4 + 3] = v.w;
    }
    __syncthreads();
#pragma unroll
    for (int p = 0; p < 4; ++p) {
        const int orow = p * 16 + r16;       // n-dim
        ushort4 o;
        o.x = f2bf(tile[c4][orow]);
        o.y = f2bf(tile[c4 + 1][orow]);
        o.z = f2bf(tile[c4 + 2][orow]);
        o.w = f2bf(tile[c4 + 3][orow]);
        *(ushort4*)(Wt + (long)(n0 + orow) * K + k0 + c4) = o;
    }
}

// ---------------- shared GEMM machinery ----------------

__device__ __forceinline__ void gld_lds16(const ushort* g, ushort* l) {
    __builtin_amdgcn_global_load_lds((const __attribute__((address_space(1))) void*)g,
                                     (__attribute__((address_space(3))) void*)l, 16, 0, 0);
}

// ---------------- GEMM, BK=64 (2 k-panels of the proven [128][32] tile per buffer) ----------------

template <bool RELU>
__global__ __launch_bounds__(256) void gemm_kernel(const ushort* __restrict__ A, const ushort* __restrict__ Bt,
                                                   const float* __restrict__ bias, ushort* __restrict__ C,
                                                   int M, int N, int K, float alpha) {
    __shared__ __align__(16) ushort As[2 * 2 * 128 * 32];   // 32 KB: [buf][panel][128][32]
    __shared__ __align__(16) ushort Bs[2 * 2 * 128 * 32];   // 32 KB
    const int tid = threadIdx.x;
    const int lane = tid & 63;
    const int wave = tid >> 6;
    const int wr = wave >> 1, wc = wave & 1;

    // XCD-locality swizzle (requires gridDim.x == 256): b -> xcd strip of 32 m-tiles
    const int b = (int)(blockIdx.y * gridDim.x + blockIdx.x);
    const int idx = b >> 3;
    const int xt = (b & 7) * 32 + (idx & 31);
    const int yt = idx >> 5;
    const long m0 = (long)xt * 128;
    const long n0 = (long)yt * 128;

    f32x4 acc[4][4] = {};

    const int rel8 = ((tid & 3) ^ ((tid >> 3) & 3)) * 8;
    const ushort* Ar0 = A + (m0 + (tid >> 2)) * K + rel8;
    const ushort* Ar1 = Ar0 + 64 * K;
    const ushort* Br0 = Bt + (n0 + (tid >> 2)) * K + rel8;
    const ushort* Br1 = Br0 + 64 * K;
    const int la = lane & 15;
    const int sx = ((lane >> 4) ^ ((la >> 1) & 3)) * 8;

    const int nt = K >> 6;
    int buf = 0;
#pragma unroll
    for (int p = 0; p < 2; ++p) {
        gld_lds16(Ar0 + p * 32, As + p * 4096 + tid * 8);
        gld_lds16(Ar1 + p * 32, As + p * 4096 + (tid + 256) * 8);
        gld_lds16(Br0 + p * 32, Bs + p * 4096 + tid * 8);
        gld_lds16(Br1 + p * 32, Bs + p * 4096 + (tid + 256) * 8);
    }

    for (int t = 0; t < nt; ++t) {
        const int bO = buf * 8192;
        if (t + 1 < nt) {
            const int kt = (t + 1) << 6;
            const int nO = (buf ^ 1) * 8192;
#pragma unroll
            for (int p = 0; p < 2; ++p) {
                gld_lds16(Ar0 + kt + p * 32, As + nO + p * 4096 + tid * 8);
                gld_lds16(Ar1 + kt + p * 32, As + nO + p * 4096 + (tid + 256) * 8);
                gld_lds16(Br0 + kt + p * 32, Bs + nO + p * 4096 + tid * 8);
                gld_lds16(Br1 + kt + p * 32, Bs + nO + p * 4096 + (tid + 256) * 8);
            }
            asm volatile("s_waitcnt vmcnt(8)" ::: "memory");   // tile t landed; t+1's 8 loads in flight
        } else {
            asm volatile("s_waitcnt vmcnt(0)" ::: "memory");
        }
        __builtin_amdgcn_s_barrier();
        s16x8 af[2][4], bfr[2][4];
#pragma unroll
        for (int kk = 0; kk < 2; ++kk) {
#pragma unroll
            for (int m = 0; m < 4; ++m)
                af[kk][m] = *(const s16x8*)(As + bO + kk * 4096 + (wr * 64 + m * 16 + la) * 32 + sx);
#pragma unroll
            for (int n = 0; n < 4; ++n)
                bfr[kk][n] = *(const s16x8*)(Bs + bO + kk * 4096 + (wc * 64 + n * 16 + la) * 32 + sx);
        }
        asm volatile("s_waitcnt lgkmcnt(0)" ::: "memory");
        __builtin_amdgcn_s_barrier();
#pragma unroll
        for (int kk = 0; kk < 2; ++kk)
#pragma unroll
            for (int m = 0; m < 4; ++m)
#pragma unroll
                for (int n = 0; n < 4; ++n)
                    acc[m][n] = __builtin_amdgcn_mfma_f32_16x16x32_bf16(af[kk][m], bfr[kk][n], acc[m][n], 0, 0, 0);
        buf ^= 1;
    }

#pragma unroll
    for (int n = 0; n < 4; ++n) {
        const long col = n0 + wc * 64 + n * 16 + la;
        const float bv = bias[col];
#pragma unroll
        for (int m = 0; m < 4; ++m) {
#pragma unroll
            for (int j = 0; j < 4; ++j) {
                const long row = m0 + wr * 64 + m * 16 + (lane >> 4) * 4 + j;
                float r = (acc[m][n][j] + bv) * alpha;
                if (RELU) r = fmaxf(r, 0.f);
                C[row * N + col] = f2bf(r);
            }
        }
    }
}

// ---------------- merged QK + V projection GEMM, BK=64: grid (256, 6) ----------------

__global__ __launch_bounds__(256) void qkv_kernel(const ushort* __restrict__ qkb, const ushort* __restrict__ srcb,
                                                  const ushort* __restrict__ WqkT, const ushort* __restrict__ WvT,
                                                  const float* __restrict__ bias2, const float* __restrict__ bv,
                                                  ushort* __restrict__ QKb, ushort* __restrict__ Vb) {
    __shared__ __align__(16) ushort As[2 * 2 * 128 * 32];
    __shared__ __align__(16) ushort Bs[2 * 2 * 128 * 32];
    const int tid = threadIdx.x;
    const int lane = tid & 63;
    const int wave = tid >> 6;
    const int wr = wave >> 1, wc = wave & 1;
    const int K = DM_;

    const bool isqk = blockIdx.y < 4;
    const ushort* A  = isqk ? qkb : srcb;
    const ushort* Bt = isqk ? WqkT : WvT;
    const float* bias = isqk ? bias2 : bv;
    ushort* C = isqk ? QKb : Vb;
    const int N = isqk ? 512 : 256;
    const int bx = (int)blockIdx.x;
    const int xt = (bx & 7) * 32 + (bx >> 3);          // XCD m-strip swizzle within the slice
    const long m0 = (long)xt * 128;
    const long n0 = (long)(isqk ? blockIdx.y : (blockIdx.y - 4)) * 128;

    f32x4 acc[4][4] = {};

    const int rel8 = ((tid & 3) ^ ((tid >> 3) & 3)) * 8;
    const ushort* Ar0 = A + (m0 + (tid >> 2)) * K + rel8;
    const ushort* Ar1 = Ar0 + 64 * K;
    const ushort* Br0 = Bt + (n0 + (tid >> 2)) * K + rel8;
    const ushort* Br1 = Br0 + 64 * K;
    const int la = lane & 15;
    const int sx = ((lane >> 4) ^ ((la >> 1) & 3)) * 8;

    const int nt = K >> 6;   // 4
    int buf = 0;
#pragma unroll
    for (int p = 0; p < 2; ++p) {
        gld_lds16(Ar0 + p * 32, As + p * 4096 + tid * 8);
        gld_lds16(Ar1 + p * 32, As + p * 4096 + (tid + 256) * 8);
        gld_lds16(Br0 + p * 32, Bs + p * 4096 + tid * 8);
        gld_lds16(Br1 + p * 32, Bs + p * 4096 + (tid + 256) * 8);
    }

    for (int t = 0; t < nt; ++t) {
        const int bO = buf * 8192;
        if (t + 1 < nt) {
            const int kt = (t + 1) << 6;
            const int nO = (buf ^ 1) * 8192;
#pragma unroll
            for (int p = 0; p < 2; ++p) {
                gld_lds16(Ar0 + kt + p * 32, As + nO + p * 4096 + tid * 8);
                gld_lds16(Ar1 + kt + p * 32, As + nO + p * 4096 + (tid + 256) * 8);
                gld_lds16(Br0 + kt + p * 32, Bs + nO + p * 4096 + tid * 8);
                gld_lds16(Br1 + kt + p * 32, Bs + nO + p * 4096 + (tid + 256) * 8);
            }
            asm volatile("s_waitcnt vmcnt(8)" ::: "memory");
        } else {
            asm volatile("s_waitcnt vmcnt(0)" ::: "memory");
        }
        __builtin_amdgcn_s_barrier();
        s16x8 af[2][4], bfr[2][4];
#pragma unroll
        for (int kk = 0; kk < 2; ++kk) {
#pragma unroll
            for (int m = 0; m < 4; ++m)
                af[kk][m] = *(const s16x8*)(As + bO + kk * 4096 + (wr * 64 + m * 16 + la) * 32 + sx);
#pragma unroll
            for (int n = 0; n < 4; ++n)
                bfr[kk][n] = *(const s16x8*)(Bs + bO + kk * 4096 + (wc * 64 + n * 16 + la) * 32 + sx);
        }
        asm volatile("s_waitcnt lgkmcnt(0)" ::: "memory");
        __builtin_amdgcn_s_barrier();
#pragma unroll
        for (int kk = 0; kk < 2; ++kk)
#pragma unroll
            for (int m = 0; m < 4; ++m)
#pragma unroll
                for (int n = 0; n < 4; ++n)
                    acc[m][n] = __builtin_amdgcn_mfma_f32_16x16x32_bf16(af[kk][m], bfr[kk][n], acc[m][n], 0, 0, 0);
        buf ^= 1;
    }

#pragma unroll
    for (int n = 0; n < 4; ++n) {
        const long col = n0 + wc * 64 + n * 16 + la;
        const float bvv = bias[col];
#pragma unroll
        for (int m = 0; m < 4; ++m) {
#pragma unroll
            for (int j = 0; j < 4; ++j) {
                const long row = m0 + wr * 64 + m * 16 + (lane >> 4) * 4 + j;
                C[row * N + col] = f2bf(acc[m][n][j] + bvv);
            }
        }
    }
}

// ---------------- fused GEMM + residual + LayerNorm, 2-phase pipelined, BK=64 (round-13) ----------------

template <bool F32OUT>
__global__ __launch_bounds__(256) void gemm_ln_kernel(const ushort* __restrict__ A, const ushort* __restrict__ Bt,
                                                      const float* __restrict__ bias,
                                                      const ushort* __restrict__ resid,
                                                      const float* __restrict__ g, const float* __restrict__ be,
                                                      void* __restrict__ outv, int K) {
    __shared__ __align__(16) ushort As[2 * 2 * 64 * 32];    // 16 KB: [buf][panel][64 rows][32 k]
    __shared__ __align__(16) ushort Bs[2 * 2 * 256 * 32];   // 64 KB: [buf][panel][256 rows][32 k]
    const int tid = threadIdx.x;
    const int lane = tid & 63;
    const int wave = tid >> 6;
    const long m0 = (long)blockIdx.x * 64;

    const int rel8 = ((tid & 3) ^ ((tid >> 3) & 3)) * 8;   // panel-invariant source k-swizzle
    const int arow = tid >> 2;                              // A row this thread stages
    const ushort* Asrc = A + (m0 + arow) * K + rel8;        // + panel*32 + kt at use
    const ushort* Bsrc[4];                                  // B rows: tid>>2 + 64*j
#pragma unroll
    for (int j = 0; j < 4; ++j)
        Bsrc[j] = Bt + (long)(arow + 64 * j) * K + rel8;

    const int la = lane & 15;
    const int sx = ((lane >> 4) ^ ((la >> 1) & 3)) * 8;

    f32x4 acc[4][4] = {};
    const int nt = K >> 6;
    int buf = 0;
    // prologue: stage tile 0 (A: panels 0,1; B: panels 0,1 x 4 row-groups)
#pragma unroll
    for (int p = 0; p < 2; ++p)
        gld_lds16(Asrc + p * 32, As + (p * 256 + tid) * 8);
#pragma unroll
    for (int i = 0; i < 8; ++i)
        gld_lds16(Bsrc[i & 3] + (i >> 2) * 32, Bs + ((i >> 2) * 1024 + (i & 3) * 256 + tid) * 8);

    for (int t = 0; t < nt; ++t) {
        const int bA = buf * 4096, bB = buf * 16384;
        if (t + 1 < nt) {
            const int kt = (t + 1) << 6;
            const int nA = (buf ^ 1) * 4096, nB = (buf ^ 1) * 16384;
#pragma unroll
            for (int p = 0; p < 2; ++p)
                gld_lds16(Asrc + kt + p * 32, As + nA + (p * 256 + tid) * 8);
#pragma unroll
            for (int i = 0; i < 8; ++i)
                gld_lds16(Bsrc[i & 3] + kt + (i >> 2) * 32, Bs + nB + ((i >> 2) * 1024 + (i & 3) * 256 + tid) * 8);
            asm volatile("s_waitcnt vmcnt(10)" ::: "memory");  // tile t landed; t+1's 10 loads in flight
        } else {
            asm volatile("s_waitcnt vmcnt(0)" ::: "memory");
        }
        __builtin_amdgcn_s_barrier();
        s16x8 af[2][4], bfr[2][4];
#pragma unroll
        for (int kk = 0; kk < 2; ++kk) {
#pragma unroll
            for (int m = 0; m < 4; ++m)
                af[kk][m] = *(const s16x8*)(As + bA + kk * 2048 + (m * 16 + la) * 32 + sx);
#pragma unroll
            for (int n = 0; n < 4; ++n)
                bfr[kk][n] = *(const s16x8*)(Bs + bB + kk * 8192 + (wave * 64 + n * 16 + la) * 32 + sx);
        }
        asm volatile("s_waitcnt lgkmcnt(0)" ::: "memory");
        __builtin_amdgcn_s_barrier();
#pragma unroll
        for (int kk = 0; kk < 2; ++kk)
#pragma unroll
            for (int m = 0; m < 4; ++m)
#pragma unroll
                for (int n = 0; n < 4; ++n)
                    acc[m][n] = __builtin_amdgcn_mfma_f32_16x16x32_bf16(af[kk][m], bfr[kk][n], acc[m][n], 0, 0, 0);
        buf ^= 1;
    }

    // epilogue: LN reduce arrays alias dead As (all LDS reads completed before the last barrier)
    float* red_s = (float*)As;          // [4][64]
    float* red_q = (float*)As + 256;    // [4][64]
    const int rg4 = (lane >> 4) * 4;
    float bv[4];
#pragma unroll
    for (int n = 0; n < 4; ++n) bv[n] = bias[wave * 64 + n * 16 + la];

#pragma unroll
    for (int m = 0; m < 4; ++m) {
#pragma unroll
        for (int j = 0; j < 4; ++j) {
            const int lr = m * 16 + rg4 + j;
            float s = 0.f, q = 0.f;
#pragma unroll
            for (int n = 0; n < 4; ++n) {
                const int col = wave * 64 + n * 16 + la;
                float v = acc[m][n][j] + bv[n] + bf2f(resid[(m0 + lr) * DM_ + col]);
                acc[m][n][j] = v;
                s += v; q += v * v;
            }
#pragma unroll
            for (int mk = 1; mk < 16; mk <<= 1) { s += __shfl_xor(s, mk); q += __shfl_xor(q, mk); }
            if (la == 0) { red_s[wave * 64 + lr] = s; red_q[wave * 64 + lr] = q; }
        }
    }
    __syncthreads();

    float gv[4], bev[4];
#pragma unroll
    for (int n = 0; n < 4; ++n) {
        const int col = wave * 64 + n * 16 + la;
        gv[n] = g[col]; bev[n] = be[col];
    }
#pragma unroll
    for (int m = 0; m < 4; ++m) {
#pragma unroll
        for (int j = 0; j < 4; ++j) {
            const int lr = m * 16 + rg4 + j;
            const float s = red_s[lr] + red_s[64 + lr] + red_s[128 + lr] + red_s[192 + lr];
            const float q = red_q[lr] + red_q[64 + lr] + red_q[128 + lr] + red_q[192 + lr];
            const float mu = s * (1.f / 256.f);
            const float rsig = rsqrtf(q * (1.f / 256.f) - mu * mu + 1e-5f);
#pragma unroll
            for (int n = 0; n < 4; ++n) {
                const int col = wave * 64 + n * 16 + la;
                const float r = (acc[m][n][j] - mu) * rsig * gv[n] + bev[n];
                if (F32OUT) ((float*)outv)[(m0 + lr) * DM_ + col] = r;
                else        ((ushort*)outv)[(m0 + lr) * DM_ + col] = f2bf(r);
            }
        }
    }
}

// ---------------- local attention: 32 lanes per query + V-prefetch + vectorized ipair ----------------

__global__ __launch_bounds__(256, 3) void attn_kernel(const ushort* __restrict__ QKb,
                                                      const ushort* __restrict__ Vb, const int* __restrict__ ipair,
                                                      const int* __restrict__ ipb, const int* __restrict__ offs,
                                                      ushort* __restrict__ Ob) {
    // grid = 4096 blocks (8 queries each); XCD swizzle: 512 consecutive blocks (one batch) per XCD
    const int blk = (blockIdx.x & 7) * (NQ_ / 8 / 8) + (blockIdx.x >> 3);
    const int lane = threadIdx.x & 63;
    const int n = blk * 8 + (threadIdx.x >> 6) * 2 + (lane >> 5);
    const size_t hoff = (size_t)(lane & 31) * 8;   // 8 ushorts = 16B per lane

    int ip[LNB_];
#pragma unroll
    for (int c = 0; c < 4; ++c) {
        int4 v = *(const int4*)(ipair + n * LNB_ + c * 4);
        ip[c * 4] = v.x; ip[c * 4 + 1] = v.y; ip[c * 4 + 2] = v.z; ip[c * 4 + 3] = v.w;
    }
    float q[8];
    {
        s16x8 v = *(const s16x8*)(QKb + (size_t)n * 512 + hoff);
#pragma unroll
        for (int e = 0; e < 8; ++e) q[e] = bf2f((ushort)v[e]);
    }
    const int off = offs[ipb[n]];
    float lg[LNB_];
    s16x8 va[LNB_];
#pragma unroll
    for (int j = 0; j < LNB_; ++j) {
        const int g = ip[j] >= 0 ? ip[j] + off : 0;   // reference: invalid -> gather row 0
        s16x8 v = *(const s16x8*)(QKb + (size_t)g * 512 + 256 + hoff);
        va[j] = *(const s16x8*)(Vb + (size_t)g * DM_ + hoff);   // prefetch V alongside K
        float p = 0.f;
#pragma unroll
        for (int e = 0; e < 8; ++e)
            p = fmaf(q[e], bf2f((ushort)v[e]), p);
        p += __shfl_xor(p, 1);                  // 4-lane head group reduce
        p += __shfl_xor(p, 2);
        lg[j] = ip[j] >= 0 ? p * 0.17677669529663688f : -1e9f;
    }
    float mx = lg[0];
#pragma unroll
    for (int j = 1; j < LNB_; ++j) mx = fmaxf(mx, lg[j]);
    float sum = 0.f, pw[LNB_];
#pragma unroll
    for (int j = 0; j < LNB_; ++j) { pw[j] = __expf(lg[j] - mx); sum += pw[j]; }
    const float inv = 1.f / sum;

    float acc[8] = {};
#pragma unroll
    for (int j = 0; j < LNB_; ++j) {
        const float w = pw[j] * inv;
#pragma unroll
        for (int e = 0; e < 8; ++e)
            acc[e] = fmaf(w, bf2f((ushort)va[j][e]), acc[e]);
    }
    s16x8 o;
#pragma unroll
    for (int e = 0; e < 8; ++e) o[e] = (short)f2bf(acc[e]);
    *(s16x8*)(Ob + (size_t)n * DM_ + hoff) = o;
}

// ---------------- launch ----------------

extern "C" void kernel_launch(void* const* d_in, const int* in_sizes, int n_in,
                              void* d_out, int out_size, void* d_ws, size_t ws_size,
                              hipStream_t stream) {
    const float* src = (const float*)d_in[0];
    const float* pos = (const float*)d_in[1];
    const int* ipair = (const int*)d_in[2];
    const int* kbc   = (const int*)d_in[4];
    const int* ipb   = (const int*)d_in[5];
    const float* Wq = (const float*)d_in[6];  const float* bq = (const float*)d_in[7];
    const float* Wk = (const float*)d_in[8];  const float* bk = (const float*)d_in[9];
    const float* Wv = (const float*)d_in[10]; const float* bv = (const float*)d_in[11];
    const float* Wo = (const float*)d_in[12]; const float* bo = (const float*)d_in[13];
    const float* W1 = (const float*)d_in[14]; const float* b1 = (const float*)d_in[15];
    const float* W2 = (const float*)d_in[16]; const float* b2 = (const float*)d_in[17];
    const float* g1 = (const float*)d_in[18]; const float* be1 = (const float*)d_in[19];
    const float* g2 = (const float*)d_in[20]; const float* be2 = (const float*)d_in[21];

    char* ws = (char*)d_ws;
    const size_t SB = (size_t)NQ_ * DM_ * 2;   // 16 MiB per [NQ,256] bf16 buffer
    ushort* qkb  = (ushort*)(ws);              // src+pos bf16; later: attn-out
    ushort* srcb = (ushort*)(ws + SB);         // src bf16; live until Wo+ln1 (residual)
    ushort* QKb  = (ushort*)(ws + 2 * SB);     // fused QK out [NQ,512] (2 SB)
    ushort* Vb   = (ushort*)(ws + 4 * SB);     // V out; later: xb
    ushort* hb   = (ushort*)(ws);              // FF hidden [NQ,1024] spans first 4 SB (all dead by then)
    ushort* attno = qkb;
    ushort* xb    = Vb;                        // Vb dead after attn; Wo+ln1 writes xb here
    char* wb = ws + 6 * SB;
    ushort* WqT = (ushort*)(wb);               // [256][256] — WkT directly after => fused [512][256]
    ushort* WkT = (ushort*)(wb + 131072);
    ushort* WvT = (ushort*)(wb + 262144);
    ushort* WoT = (ushort*)(wb + 393216);
    ushort* W1T = (ushort*)(wb + 524288);
    ushort* W2T = (ushort*)(wb + 1048576);
    int* offs   = (int*)(wb + 1572864);
    float* bias2 = (float*)(wb + 1572864 + 64);

    prep_all<<<8192 + 192 + 1, 256, 0, stream>>>(src, pos, qkb, srcb,
                                                 Wq, Wk, Wv, Wo, W1, W2, kbc, bq, bk,
                                                 WqT, WkT, WvT, WoT, W1T, W2T, offs, bias2);

    dim3 gqkv(256, 6);
    dim3 gff1(NQ_ / 128, DFF_ / 128);
    qkv_kernel<<<gqkv, 256, 0, stream>>>(qkb, srcb, WqT, WvT, bias2, bv, QKb, Vb);
    attn_kernel<<<NQ_ / 8, 256, 0, stream>>>(QKb, Vb, ipair, ipb, offs, attno);
    // Wo projection + residual(srcb) + LN1 -> xb (bf16)
    gemm_ln_kernel<false><<<NQ_ / 64, 256, 0, stream>>>(attno, WoT, bo, srcb, g1, be1, (void*)xb, DM_);
    gemm_kernel<true><<<gff1, 256, 0, stream>>>(xb, W1T, b1, hb, NQ_, DFF_, DM_, 1.f);
    // FF2 + residual(xb) + LN2 -> d_out (f32)
    gemm_ln_kernel<true><<<NQ_ / 64, 256, 0, stream>>>(hb, W2T, b2, xb, g2, be2, d_out, DFF_);
}

// Round 18
// 161.970 us; speedup vs baseline: 1.1351x; 1.0100x over previous
//
#include <hip/hip_runtime.h>
#include <hip/hip_bf16.h>
#include <cstdint>
#include <cstddef>

#define NQ_ 32768
#define DM_ 256
#define DFF_ 1024
#define LNB_ 16
#define NB_ 8

typedef __attribute__((ext_vector_type(4))) float f32x4;
typedef __attribute__((ext_vector_type(8))) short s16x8;

__device__ __forceinline__ float bf2f(ushort u) {
    union { unsigned int i; float f; } c; c.i = ((unsigned int)u) << 16; return c.f;
}
__device__ __forceinline__ ushort f2bf(float f) {
    union { float f; unsigned int i; } c; c.f = f;
    unsigned int x = c.i;
    return (ushort)((x + 0x7fffu + ((x >> 16) & 1u)) >> 16); // RNE
}

// ---------------- merged prep ----------------
// blocks 0..8191: src/pos cast+add (coalesced float4)
// blocks 8192..8383: weight transposes via LDS-tiled 64x64 transpose (coalesced both sides)
// block 8384: batch-offset scan + fused QK bias

__global__ __launch_bounds__(256) void prep_all(const float* __restrict__ src, const float* __restrict__ pos,
                                                ushort* __restrict__ qkb, ushort* __restrict__ srcb,
                                                const float* __restrict__ Wq, const float* __restrict__ Wk,
                                                const float* __restrict__ Wv, const float* __restrict__ Wo,
                                                const float* __restrict__ W1, const float* __restrict__ W2,
                                                const int* __restrict__ kbc,
                                                const float* __restrict__ bq, const float* __restrict__ bk,
                                                ushort* __restrict__ WqT, ushort* __restrict__ WkT,
                                                ushort* __restrict__ WvT, ushort* __restrict__ WoT,
                                                ushort* __restrict__ W1T, ushort* __restrict__ W2T,
                                                int* __restrict__ offs, float* __restrict__ bias2) {
    const int blk = blockIdx.x;
    const int t = threadIdx.x;
    if (blk < 8192) {
        const int i = (blk * 256 + t) * 4;
        float4 s = *(const float4*)(src + i);
        float4 p = *(const float4*)(pos + i);
        ushort4 a, b;
        a.x = f2bf(s.x + p.x); a.y = f2bf(s.y + p.y); a.z = f2bf(s.z + p.z); a.w = f2bf(s.w + p.w);
        b.x = f2bf(s.x);       b.y = f2bf(s.y);       b.z = f2bf(s.z);       b.w = f2bf(s.w);
        *(ushort4*)(qkb + i) = a;
        *(ushort4*)(srcb + i) = b;
        return;
    }
    if (blk == 8384) {
        if (t == 0) { int a = 0; for (int i = 0; i < NB_; ++i) { offs[i] = a; a += kbc[i]; } }
        bias2[t] = bq[t];
        bias2[256 + t] = bk[t];
        return;
    }
    // ---- tiled transpose: W [K][N] f32 -> Wt [N][K] bf16, 64x64 tiles ----
    __shared__ float tile[64][65];
    const int tb = blk - 8192;        // 0..191
    const float* W; ushort* Wt; int K, N, kt, ntl;
    if (tb < 64) {                    // Wq/Wk/Wv/Wo [256][256]
        const int sec = tb >> 4;
        W  = sec == 0 ? Wq  : sec == 1 ? Wk  : sec == 2 ? Wv  : Wo;
        Wt = sec == 0 ? WqT : sec == 1 ? WkT : sec == 2 ? WvT : WoT;
        K = 256; N = 256; kt = (tb & 15) >> 2; ntl = tb & 3;
    } else if (tb < 128) {            // W1 [256][1024]
        W = W1; Wt = W1T; K = 256; N = 1024;
        const int r = tb - 64; kt = r >> 4; ntl = r & 15;
    } else {                          // W2 [1024][256]
        W = W2; Wt = W2T; K = 1024; N = 256;
        const int r = tb - 128; kt = r >> 2; ntl = r & 3;
    }
    const int k0 = kt * 64, n0 = ntl * 64;
    const int r16 = t >> 4, c4 = (t & 15) * 4;
#pragma unroll
    for (int p = 0; p < 4; ++p) {
        const int row = p * 16 + r16;
        float4 v = *(const float4*)(W + (long)(k0 + row) * N + n0 + c4);
        tile[row][c4] = v.x; tile[row][c4 + 1] = v.y; tile[row][c4 + 2] = v.z; tile[row][c4 + 3] = v.w;
    }
    __syncthreads();
#pragma unroll
    for (int p = 0; p < 4; ++p) {
        const int orow = p * 16 + r16;       // n-dim
        ushort4 o;
        o.x = f2bf(tile[c4][orow]);
        o.y = f2bf(tile[c4 + 1][orow]);
        o.z = f2bf(tile[c4 + 2][orow]);
        o.w = f2bf(tile[c4 + 3][orow]);
        *(ushort4*)(Wt + (long)(n0 + orow) * K + k0 + c4) = o;
    }
}

// ---------------- shared GEMM machinery ----------------

__device__ __forceinline__ void gld_lds16(const ushort* g, ushort* l) {
    __builtin_amdgcn_global_load_lds((const __attribute__((address_space(1))) void*)g,
                                     (__attribute__((address_space(3))) void*)l, 16, 0, 0);
}

// ---------------- GEMM, BK=64 (2 k-panels of the proven [128][32] tile per buffer) ----------------

template <bool RELU>
__global__ __launch_bounds__(256) void gemm_kernel(const ushort* __restrict__ A, const ushort* __restrict__ Bt,
                                                   const float* __restrict__ bias, ushort* __restrict__ C,
                                                   int M, int N, int K, float alpha) {
    __shared__ __align__(16) ushort As[2 * 2 * 128 * 32];   // 32 KB: [buf][panel][128][32]
    __shared__ __align__(16) ushort Bs[2 * 2 * 128 * 32];   // 32 KB
    const int tid = threadIdx.x;
    const int lane = tid & 63;
    const int wave = tid >> 6;
    const int wr = wave >> 1, wc = wave & 1;

    // XCD-locality swizzle (requires gridDim.x == 256): b -> xcd strip of 32 m-tiles
    const int b = (int)(blockIdx.y * gridDim.x + blockIdx.x);
    const int idx = b >> 3;
    const int xt = (b & 7) * 32 + (idx & 31);
    const int yt = idx >> 5;
    const long m0 = (long)xt * 128;
    const long n0 = (long)yt * 128;

    f32x4 acc[4][4] = {};

    const int rel8 = ((tid & 3) ^ ((tid >> 3) & 3)) * 8;
    const ushort* Ar0 = A + (m0 + (tid >> 2)) * K + rel8;
    const ushort* Ar1 = Ar0 + 64 * K;
    const ushort* Br0 = Bt + (n0 + (tid >> 2)) * K + rel8;
    const ushort* Br1 = Br0 + 64 * K;
    const int la = lane & 15;
    const int sx = ((lane >> 4) ^ ((la >> 1) & 3)) * 8;

    const int nt = K >> 6;
    int buf = 0;
#pragma unroll
    for (int p = 0; p < 2; ++p) {
        gld_lds16(Ar0 + p * 32, As + p * 4096 + tid * 8);
        gld_lds16(Ar1 + p * 32, As + p * 4096 + (tid + 256) * 8);
        gld_lds16(Br0 + p * 32, Bs + p * 4096 + tid * 8);
        gld_lds16(Br1 + p * 32, Bs + p * 4096 + (tid + 256) * 8);
    }

    for (int t = 0; t < nt; ++t) {
        const int bO = buf * 8192;
        if (t + 1 < nt) {
            const int kt = (t + 1) << 6;
            const int nO = (buf ^ 1) * 8192;
#pragma unroll
            for (int p = 0; p < 2; ++p) {
                gld_lds16(Ar0 + kt + p * 32, As + nO + p * 4096 + tid * 8);
                gld_lds16(Ar1 + kt + p * 32, As + nO + p * 4096 + (tid + 256) * 8);
                gld_lds16(Br0 + kt + p * 32, Bs + nO + p * 4096 + tid * 8);
                gld_lds16(Br1 + kt + p * 32, Bs + nO + p * 4096 + (tid + 256) * 8);
            }
            asm volatile("s_waitcnt vmcnt(8)" ::: "memory");   // tile t landed; t+1's 8 loads in flight
        } else {
            asm volatile("s_waitcnt vmcnt(0)" ::: "memory");
        }
        __builtin_amdgcn_s_barrier();
        s16x8 af[2][4], bfr[2][4];
#pragma unroll
        for (int kk = 0; kk < 2; ++kk) {
#pragma unroll
            for (int m = 0; m < 4; ++m)
                af[kk][m] = *(const s16x8*)(As + bO + kk * 4096 + (wr * 64 + m * 16 + la) * 32 + sx);
#pragma unroll
            for (int n = 0; n < 4; ++n)
                bfr[kk][n] = *(const s16x8*)(Bs + bO + kk * 4096 + (wc * 64 + n * 16 + la) * 32 + sx);
        }
        asm volatile("s_waitcnt lgkmcnt(0)" ::: "memory");
        __builtin_amdgcn_s_barrier();
#pragma unroll
        for (int kk = 0; kk < 2; ++kk)
#pragma unroll
            for (int m = 0; m < 4; ++m)
#pragma unroll
                for (int n = 0; n < 4; ++n)
                    acc[m][n] = __builtin_amdgcn_mfma_f32_16x16x32_bf16(af[kk][m], bfr[kk][n], acc[m][n], 0, 0, 0);
        buf ^= 1;
    }

#pragma unroll
    for (int n = 0; n < 4; ++n) {
        const long col = n0 + wc * 64 + n * 16 + la;
        const float bv = bias[col];
#pragma unroll
        for (int m = 0; m < 4; ++m) {
#pragma unroll
            for (int j = 0; j < 4; ++j) {
                const long row = m0 + wr * 64 + m * 16 + (lane >> 4) * 4 + j;
                float r = (acc[m][n][j] + bv) * alpha;
                if (RELU) r = fmaxf(r, 0.f);
                C[row * N + col] = f2bf(r);
            }
        }
    }
}

// ---------------- merged QK + V projection GEMM, BK=64: grid (256, 6) ----------------

__global__ __launch_bounds__(256) void qkv_kernel(const ushort* __restrict__ qkb, const ushort* __restrict__ srcb,
                                                  const ushort* __restrict__ WqkT, const ushort* __restrict__ WvT,
                                                  const float* __restrict__ bias2, const float* __restrict__ bv,
                                                  ushort* __restrict__ QKb, ushort* __restrict__ Vb) {
    __shared__ __align__(16) ushort As[2 * 2 * 128 * 32];
    __shared__ __align__(16) ushort Bs[2 * 2 * 128 * 32];
    const int tid = threadIdx.x;
    const int lane = tid & 63;
    const int wave = tid >> 6;
    const int wr = wave >> 1, wc = wave & 1;
    const int K = DM_;

    const bool isqk = blockIdx.y < 4;
    const ushort* A  = isqk ? qkb : srcb;
    const ushort* Bt = isqk ? WqkT : WvT;
    const float* bias = isqk ? bias2 : bv;
    ushort* C = isqk ? QKb : Vb;
    const int N = isqk ? 512 : 256;
    const int bx = (int)blockIdx.x;
    const int xt = (bx & 7) * 32 + (bx >> 3);          // XCD m-strip swizzle within the slice
    const long m0 = (long)xt * 128;
    const long n0 = (long)(isqk ? blockIdx.y : (blockIdx.y - 4)) * 128;

    f32x4 acc[4][4] = {};

    const int rel8 = ((tid & 3) ^ ((tid >> 3) & 3)) * 8;
    const ushort* Ar0 = A + (m0 + (tid >> 2)) * K + rel8;
    const ushort* Ar1 = Ar0 + 64 * K;
    const ushort* Br0 = Bt + (n0 + (tid >> 2)) * K + rel8;
    const ushort* Br1 = Br0 + 64 * K;
    const int la = lane & 15;
    const int sx = ((lane >> 4) ^ ((la >> 1) & 3)) * 8;

    const int nt = K >> 6;   // 4
    int buf = 0;
#pragma unroll
    for (int p = 0; p < 2; ++p) {
        gld_lds16(Ar0 + p * 32, As + p * 4096 + tid * 8);
        gld_lds16(Ar1 + p * 32, As + p * 4096 + (tid + 256) * 8);
        gld_lds16(Br0 + p * 32, Bs + p * 4096 + tid * 8);
        gld_lds16(Br1 + p * 32, Bs + p * 4096 + (tid + 256) * 8);
    }

    for (int t = 0; t < nt; ++t) {
        const int bO = buf * 8192;
        if (t + 1 < nt) {
            const int kt = (t + 1) << 6;
            const int nO = (buf ^ 1) * 8192;
#pragma unroll
            for (int p = 0; p < 2; ++p) {
                gld_lds16(Ar0 + kt + p * 32, As + nO + p * 4096 + tid * 8);
                gld_lds16(Ar1 + kt + p * 32, As + nO + p * 4096 + (tid + 256) * 8);
                gld_lds16(Br0 + kt + p * 32, Bs + nO + p * 4096 + tid * 8);
                gld_lds16(Br1 + kt + p * 32, Bs + nO + p * 4096 + (tid + 256) * 8);
            }
            asm volatile("s_waitcnt vmcnt(8)" ::: "memory");
        } else {
            asm volatile("s_waitcnt vmcnt(0)" ::: "memory");
        }
        __builtin_amdgcn_s_barrier();
        s16x8 af[2][4], bfr[2][4];
#pragma unroll
        for (int kk = 0; kk < 2; ++kk) {
#pragma unroll
            for (int m = 0; m < 4; ++m)
                af[kk][m] = *(const s16x8*)(As + bO + kk * 4096 + (wr * 64 + m * 16 + la) * 32 + sx);
#pragma unroll
            for (int n = 0; n < 4; ++n)
                bfr[kk][n] = *(const s16x8*)(Bs + bO + kk * 4096 + (wc * 64 + n * 16 + la) * 32 + sx);
        }
        asm volatile("s_waitcnt lgkmcnt(0)" ::: "memory");
        __builtin_amdgcn_s_barrier();
#pragma unroll
        for (int kk = 0; kk < 2; ++kk)
#pragma unroll
            for (int m = 0; m < 4; ++m)
#pragma unroll
                for (int n = 0; n < 4; ++n)
                    acc[m][n] = __builtin_amdgcn_mfma_f32_16x16x32_bf16(af[kk][m], bfr[kk][n], acc[m][n], 0, 0, 0);
        buf ^= 1;
    }

#pragma unroll
    for (int n = 0; n < 4; ++n) {
        const long col = n0 + wc * 64 + n * 16 + la;
        const float bvv = bias[col];
#pragma unroll
        for (int m = 0; m < 4; ++m) {
#pragma unroll
            for (int j = 0; j < 4; ++j) {
                const long row = m0 + wr * 64 + m * 16 + (lane >> 4) * 4 + j;
                C[row * N + col] = f2bf(acc[m][n][j] + bvv);
            }
        }
    }
}

// ---------------- fused GEMM + residual + LayerNorm, 2-phase pipelined, BK=64 (round-13) ----------------

template <bool F32OUT>
__global__ __launch_bounds__(256) void gemm_ln_kernel(const ushort* __restrict__ A, const ushort* __restrict__ Bt,
                                                      const float* __restrict__ bias,
                                                      const ushort* __restrict__ resid,
                                                      const float* __restrict__ g, const float* __restrict__ be,
                                                      void* __restrict__ outv, int K) {
    __shared__ __align__(16) ushort As[2 * 2 * 64 * 32];    // 16 KB: [buf][panel][64 rows][32 k]
    __shared__ __align__(16) ushort Bs[2 * 2 * 256 * 32];   // 64 KB: [buf][panel][256 rows][32 k]
    const int tid = threadIdx.x;
    const int lane = tid & 63;
    const int wave = tid >> 6;
    const long m0 = (long)blockIdx.x * 64;

    const int rel8 = ((tid & 3) ^ ((tid >> 3) & 3)) * 8;   // panel-invariant source k-swizzle
    const int arow = tid >> 2;                              // A row this thread stages
    const ushort* Asrc = A + (m0 + arow) * K + rel8;        // + panel*32 + kt at use
    const ushort* Bsrc[4];                                  // B rows: tid>>2 + 64*j
#pragma unroll
    for (int j = 0; j < 4; ++j)
        Bsrc[j] = Bt + (long)(arow + 64 * j) * K + rel8;

    const int la = lane & 15;
    const int sx = ((lane >> 4) ^ ((la >> 1) & 3)) * 8;

    f32x4 acc[4][4] = {};
    const int nt = K >> 6;
    int buf = 0;
    // prologue: stage tile 0 (A: panels 0,1; B: panels 0,1 x 4 row-groups)
#pragma unroll
    for (int p = 0; p < 2; ++p)
        gld_lds16(Asrc + p * 32, As + (p * 256 + tid) * 8);
#pragma unroll
    for (int i = 0; i < 8; ++i)
        gld_lds16(Bsrc[i & 3] + (i >> 2) * 32, Bs + ((i >> 2) * 1024 + (i & 3) * 256 + tid) * 8);

    for (int t = 0; t < nt; ++t) {
        const int bA = buf * 4096, bB = buf * 16384;
        if (t + 1 < nt) {
            const int kt = (t + 1) << 6;
            const int nA = (buf ^ 1) * 4096, nB = (buf ^ 1) * 16384;
#pragma unroll
            for (int p = 0; p < 2; ++p)
                gld_lds16(Asrc + kt + p * 32, As + nA + (p * 256 + tid) * 8);
#pragma unroll
            for (int i = 0; i < 8; ++i)
                gld_lds16(Bsrc[i & 3] + kt + (i >> 2) * 32, Bs + nB + ((i >> 2) * 1024 + (i & 3) * 256 + tid) * 8);
            asm volatile("s_waitcnt vmcnt(10)" ::: "memory");  // tile t landed; t+1's 10 loads in flight
        } else {
            asm volatile("s_waitcnt vmcnt(0)" ::: "memory");
        }
        __builtin_amdgcn_s_barrier();
        s16x8 af[2][4], bfr[2][4];
#pragma unroll
        for (int kk = 0; kk < 2; ++kk) {
#pragma unroll
            for (int m = 0; m < 4; ++m)
                af[kk][m] = *(const s16x8*)(As + bA + kk * 2048 + (m * 16 + la) * 32 + sx);
#pragma unroll
            for (int n = 0; n < 4; ++n)
                bfr[kk][n] = *(const s16x8*)(Bs + bB + kk * 8192 + (wave * 64 + n * 16 + la) * 32 + sx);
        }
        asm volatile("s_waitcnt lgkmcnt(0)" ::: "memory");
        __builtin_amdgcn_s_barrier();
#pragma unroll
        for (int kk = 0; kk < 2; ++kk)
#pragma unroll
            for (int m = 0; m < 4; ++m)
#pragma unroll
                for (int n = 0; n < 4; ++n)
                    acc[m][n] = __builtin_amdgcn_mfma_f32_16x16x32_bf16(af[kk][m], bfr[kk][n], acc[m][n], 0, 0, 0);
        buf ^= 1;
    }

    // epilogue: LN reduce arrays alias dead As (all LDS reads completed before the last barrier)
    float* red_s = (float*)As;          // [4][64]
    float* red_q = (float*)As + 256;    // [4][64]
    const int rg4 = (lane >> 4) * 4;
    float bv[4];
#pragma unroll
    for (int n = 0; n < 4; ++n) bv[n] = bias[wave * 64 + n * 16 + la];

#pragma unroll
    for (int m = 0; m < 4; ++m) {
#pragma unroll
        for (int j = 0; j < 4; ++j) {
            const int lr = m * 16 + rg4 + j;
            float s = 0.f, q = 0.f;
#pragma unroll
            for (int n = 0; n < 4; ++n) {
                const int col = wave * 64 + n * 16 + la;
                float v = acc[m][n][j] + bv[n] + bf2f(resid[(m0 + lr) * DM_ + col]);
                acc[m][n][j] = v;
                s += v; q += v * v;
            }
#pragma unroll
            for (int mk = 1; mk < 16; mk <<= 1) { s += __shfl_xor(s, mk); q += __shfl_xor(q, mk); }
            if (la == 0) { red_s[wave * 64 + lr] = s; red_q[wave * 64 + lr] = q; }
        }
    }
    __syncthreads();

    float gv[4], bev[4];
#pragma unroll
    for (int n = 0; n < 4; ++n) {
        const int col = wave * 64 + n * 16 + la;
        gv[n] = g[col]; bev[n] = be[col];
    }
#pragma unroll
    for (int m = 0; m < 4; ++m) {
#pragma unroll
        for (int j = 0; j < 4; ++j) {
            const int lr = m * 16 + rg4 + j;
            const float s = red_s[lr] + red_s[64 + lr] + red_s[128 + lr] + red_s[192 + lr];
            const float q = red_q[lr] + red_q[64 + lr] + red_q[128 + lr] + red_q[192 + lr];
            const float mu = s * (1.f / 256.f);
            const float rsig = rsqrtf(q * (1.f / 256.f) - mu * mu + 1e-5f);
#pragma unroll
            for (int n = 0; n < 4; ++n) {
                const int col = wave * 64 + n * 16 + la;
                const float r = (acc[m][n][j] - mu) * rsig * gv[n] + bev[n];
                if (F32OUT) ((float*)outv)[(m0 + lr) * DM_ + col] = r;
                else        ((ushort*)outv)[(m0 + lr) * DM_ + col] = f2bf(r);
            }
        }
    }
}

// ---------------- local attention: 32 lanes per query + V-prefetch + vectorized ipair ----------------
// launch_bounds(256,4): ~115-120 VGPR body fits the 128 cap; 16 waves/CU to hide gather latency.

__global__ __launch_bounds__(256, 4) void attn_kernel(const ushort* __restrict__ QKb,
                                                      const ushort* __restrict__ Vb, const int* __restrict__ ipair,
                                                      const int* __restrict__ ipb, const int* __restrict__ offs,
                                                      ushort* __restrict__ Ob) {
    // grid = 4096 blocks (8 queries each); XCD swizzle: 512 consecutive blocks (one batch) per XCD
    const int blk = (blockIdx.x & 7) * (NQ_ / 8 / 8) + (blockIdx.x >> 3);
    const int lane = threadIdx.x & 63;
    const int n = blk * 8 + (threadIdx.x >> 6) * 2 + (lane >> 5);
    const size_t hoff = (size_t)(lane & 31) * 8;   // 8 ushorts = 16B per lane

    int ip[LNB_];
#pragma unroll
    for (int c = 0; c < 4; ++c) {
        int4 v = *(const int4*)(ipair + n * LNB_ + c * 4);
        ip[c * 4] = v.x; ip[c * 4 + 1] = v.y; ip[c * 4 + 2] = v.z; ip[c * 4 + 3] = v.w;
    }
    float q[8];
    {
        s16x8 v = *(const s16x8*)(QKb + (size_t)n * 512 + hoff);
#pragma unroll
        for (int e = 0; e < 8; ++e) q[e] = bf2f((ushort)v[e]);
    }
    const int off = offs[ipb[n]];
    float lg[LNB_];
    s16x8 va[LNB_];
#pragma unroll
    for (int j = 0; j < LNB_; ++j) {
        const int g = ip[j] >= 0 ? ip[j] + off : 0;   // reference: invalid -> gather row 0
        s16x8 v = *(const s16x8*)(QKb + (size_t)g * 512 + 256 + hoff);
        va[j] = *(const s16x8*)(Vb + (size_t)g * DM_ + hoff);   // prefetch V alongside K
        float p = 0.f;
#pragma unroll
        for (int e = 0; e < 8; ++e)
            p = fmaf(q[e], bf2f((ushort)v[e]), p);
        p += __shfl_xor(p, 1);                  // 4-lane head group reduce
        p += __shfl_xor(p, 2);
        lg[j] = ip[j] >= 0 ? p * 0.17677669529663688f : -1e9f;
    }
    float mx = lg[0];
#pragma unroll
    for (int j = 1; j < LNB_; ++j) mx = fmaxf(mx, lg[j]);
    float sum = 0.f, pw[LNB_];
#pragma unroll
    for (int j = 0; j < LNB_; ++j) { pw[j] = __expf(lg[j] - mx); sum += pw[j]; }
    const float inv = 1.f / sum;

    float acc[8] = {};
#pragma unroll
    for (int j = 0; j < LNB_; ++j) {
        const float w = pw[j] * inv;
#pragma unroll
        for (int e = 0; e < 8; ++e)
            acc[e] = fmaf(w, bf2f((ushort)va[j][e]), acc[e]);
    }
    s16x8 o;
#pragma unroll
    for (int e = 0; e < 8; ++e) o[e] = (short)f2bf(acc[e]);
    *(s16x8*)(Ob + (size_t)n * DM_ + hoff) = o;
}

// ---------------- launch ----------------

extern "C" void kernel_launch(void* const* d_in, const int* in_sizes, int n_in,
                              void* d_out, int out_size, void* d_ws, size_t ws_size,
                              hipStream_t stream) {
    const float* src = (const float*)d_in[0];
    const float* pos = (const float*)d_in[1];
    const int* ipair = (const int*)d_in[2];
    const int* kbc   = (const int*)d_in[4];
    const int* ipb   = (const int*)d_in[5];
    const float* Wq = (const float*)d_in[6];  const float* bq = (const float*)d_in[7];
    const float* Wk = (const float*)d_in[8];  const float* bk = (const float*)d_in[9];
    const float* Wv = (const float*)d_in[10]; const float* bv = (const float*)d_in[11];
    const float* Wo = (const float*)d_in[12]; const float* bo = (const float*)d_in[13];
    const float* W1 = (const float*)d_in[14]; const float* b1 = (const float*)d_in[15];
    const float* W2 = (const float*)d_in[16]; const float* b2 = (const float*)d_in[17];
    const float* g1 = (const float*)d_in[18]; const float* be1 = (const float*)d_in[19];
    const float* g2 = (const float*)d_in[20]; const float* be2 = (const float*)d_in[21];

    char* ws = (char*)d_ws;
    const size_t SB = (size_t)NQ_ * DM_ * 2;   // 16 MiB per [NQ,256] bf16 buffer
    ushort* qkb  = (ushort*)(ws);              // src+pos bf16; later: attn-out
    ushort* srcb = (ushort*)(ws + SB);         // src bf16; live until Wo+ln1 (residual)
    ushort* QKb  = (ushort*)(ws + 2 * SB);     // fused QK out [NQ,512] (2 SB)
    ushort* Vb   = (ushort*)(ws + 4 * SB);     // V out; later: xb
    ushort* hb   = (ushort*)(ws);              // FF hidden [NQ,1024] spans first 4 SB (all dead by then)
    ushort* attno = qkb;
    ushort* xb    = Vb;                        // Vb dead after attn; Wo+ln1 writes xb here
    char* wb = ws + 6 * SB;
    ushort* WqT = (ushort*)(wb);               // [256][256] — WkT directly after => fused [512][256]
    ushort* WkT = (ushort*)(wb + 131072);
    ushort* WvT = (ushort*)(wb + 262144);
    ushort* WoT = (ushort*)(wb + 393216);
    ushort* W1T = (ushort*)(wb + 524288);
    ushort* W2T = (ushort*)(wb + 1048576);
    int* offs   = (int*)(wb + 1572864);
    float* bias2 = (float*)(wb + 1572864 + 64);

    prep_all<<<8192 + 192 + 1, 256, 0, stream>>>(src, pos, qkb, srcb,
                                                 Wq, Wk, Wv, Wo, W1, W2, kbc, bq, bk,
                                                 WqT, WkT, WvT, WoT, W1T, W2T, offs, bias2);

    dim3 gqkv(256, 6);
    dim3 gff1(NQ_ / 128, DFF_ / 128);
    qkv_kernel<<<gqkv, 256, 0, stream>>>(qkb, srcb, WqT, WvT, bias2, bv, QKb, Vb);
    attn_kernel<<<NQ_ / 8, 256, 0, stream>>>(QKb, Vb, ipair, ipb, offs, attno);
    // Wo projection + residual(srcb) + LN1 -> xb (bf16)
    gemm_ln_kernel<false><<<NQ_ / 64, 256, 0, stream>>>(attno, WoT, bo, srcb, g1, be1, (void*)xb, DM_);
    gemm_kernel<true><<<gff1, 256, 0, stream>>>(xb, W1T, b1, hb, NQ_, DFF_, DM_, 1.f);
    // FF2 + residual(xb) + LN2 -> d_out (f32)
    gemm_ln_kernel<true><<<NQ_ / 64, 256, 0, stream>>>(hb, W2T, b2, xb, g2, be2, d_out, DFF_);
}